// Round 4
// baseline (3882.814 us; speedup 1.0000x reference)
//
#include <hip/hip_runtime.h>
#include <hip/hip_bf16.h>

// ---------------------------------------------------------------------------
// UNet3D dense forward, round 4: LDS-tiled register-blocked direct convs.
//  - block stages an input spatial tile (+halo) for a chunk of ci in LDS;
//    each thread computes 1 output point x CT output channels.
//  - weights [tap][ci][co] -> wave-uniform scalar loads.
//  - stride-2 tconv in 8-octant form (uniform taps per block, no divergence).
//  - bf16 activations (fp32 accumulate), virtual concats via split inputs.
// ---------------------------------------------------------------------------

using bf16 = __hip_bfloat16;
using ushort8 = unsigned short __attribute__((ext_vector_type(8)));

#define TPB 256

static inline int cdiv_l(long a, int b){ return (int)((a + b - 1) / b); }

__device__ __forceinline__ float b2f(unsigned short u){
  union { unsigned int i; float f; } v; v.i = ((unsigned int)u) << 16; return v.f;
}
__device__ __forceinline__ unsigned short f2b(float f){
  union { bf16 h; unsigned short u; } v; v.h = __float2bfloat16(f); return v.u;
}
__device__ __forceinline__ float toF(float v){ return v; }
__device__ __forceinline__ float toF(bf16 v){ return __bfloat162float(v); }

template <typename T> __device__ __forceinline__ T zval();
template <> __device__ __forceinline__ float zval<float>(){ return 0.f; }
template <> __device__ __forceinline__ bf16 zval<bf16>(){ return __float2bfloat16(0.f); }

// ---------------- weight repack: OIDHW -> [tap][ci][co] ----------------
__global__ void repack_k(const float* __restrict__ w, float* __restrict__ wt,
                         int Cin, int Cout){
  int idx = blockIdx.x * blockDim.x + threadIdx.x;
  int tot = 27 * Cin * Cout;
  if (idx >= tot) return;
  int co = idx % Cout; int t = idx / Cout;
  int ci = t % Cin;    int tap = t / Cin;
  wt[idx] = w[((long)co * Cin + ci) * 27 + tap];
}

// ---------------- stride-1 3x3x3 conv pad 1, LDS-tiled ----------------
// tile: 4(d) x 4(h) x 16(w) outputs; halo 1 -> LDS (6,6,18) per ci.
template <typename Tin, typename Tout, int CT, int CC>
__global__ __launch_bounds__(TPB) void conv_s1_t(
    const Tin* __restrict__ inA, int CA, const Tin* __restrict__ inB, int CB,
    const float* __restrict__ wt, Tout* __restrict__ out,
    int N, int Cout, int D) {
  const int TD = 4, TH = 4, TW = 16;
  const int LD = TD + 2, LH = TH + 2, LW = TW + 2;        // 6,6,18
  const int V = LD * LH * LW;                             // 648
  __shared__ Tin lds[CC * V];
  int tid = threadIdx.x;
  int tw = tid & 15, th = (tid >> 4) & 3, td = tid >> 6;
  int ntW = D / TW, ntH = D / TH, ntD = D / TD;
  int bx = blockIdx.x;
  int w0 = (bx % ntW) * TW; bx /= ntW;
  int h0 = (bx % ntH) * TH; bx /= ntH;
  int d0 = (bx % ntD) * TD;
  int n  = bx / ntD;
  int co0 = blockIdx.y * CT;
  int Cin = CA + CB;
  long sp = (long)D * D * D;
  const Tin* bA = inA + (long)n * CA * sp;
  const Tin* bB = inB ? inB + (long)n * CB * sp : nullptr;

  float acc[CT];
#pragma unroll
  for (int i = 0; i < CT; ++i) acc[i] = 0.f;

  for (int ci0 = 0; ci0 < Cin; ci0 += CC) {
    __syncthreads();
    for (int idx = tid; idx < CC * V; idx += TPB) {
      int cc = idx / V; int r = idx % V;
      int zd = r / (LH * LW); int rr = r % (LH * LW);
      int zh = rr / LW; int zw = rr % LW;
      int gd = d0 + zd - 1, gh = h0 + zh - 1, gw = w0 + zw - 1;
      Tin v = zval<Tin>();
      if ((unsigned)gd < (unsigned)D && (unsigned)gh < (unsigned)D && (unsigned)gw < (unsigned)D) {
        int ci = ci0 + cc;
        long off = ((long)gd * D + gh) * D + gw;
        v = (ci < CA) ? bA[(long)ci * sp + off] : bB[(long)(ci - CA) * sp + off];
      }
      lds[idx] = v;
    }
    __syncthreads();
#pragma unroll 1
    for (int cc = 0; cc < CC; ++cc) {
      const Tin* base = lds + cc * V + td * (LH * LW) + th * LW + tw;
      const float* wci = wt + (long)(ci0 + cc) * Cout + co0;
#pragma unroll
      for (int kd = 0; kd < 3; ++kd) {
#pragma unroll
        for (int kh = 0; kh < 3; ++kh) {
          const Tin* row = base + kd * (LH * LW) + kh * LW;
          float v0 = toF(row[0]), v1 = toF(row[1]), v2 = toF(row[2]);
          long tb = (long)((kd * 3 + kh) * 3) * Cin * Cout;
          const float* wp0 = wci + tb;
          const float* wp1 = wp0 + (long)Cin * Cout;
          const float* wp2 = wp1 + (long)Cin * Cout;
#pragma unroll
          for (int co = 0; co < CT; ++co)
            acc[co] += v0 * wp0[co] + v1 * wp1[co] + v2 * wp2[co];
        }
      }
    }
  }
  long obase = ((long)n * Cout + co0) * sp + (((long)(d0 + td) * D + (h0 + th)) * D + (w0 + tw));
#pragma unroll
  for (int co = 0; co < CT; ++co) {
    if constexpr (sizeof(Tout) == 2) out[obase + (long)co * sp] = __float2bfloat16(acc[co]);
    else out[obase + (long)co * sp] = acc[co];
  }
}

// ---------------- stride-2 3x3x3 conv pad 1, LDS-tiled ----------------
// tile: 4x4x16 outputs; input span (9,9,33) per ci.
template <int CT, int CC>
__global__ __launch_bounds__(TPB) void conv_s2_t(
    const bf16* __restrict__ in, const float* __restrict__ wt, bf16* __restrict__ out,
    int N, int Cin, int Cout, int Do) {
  const int TD = 4, TH = 4, TW = 16;
  const int LD = 2 * TD + 1, LH = 2 * TH + 1, LW = 2 * TW + 1;  // 9,9,33
  const int V = LD * LH * LW;                                    // 2673
  __shared__ bf16 lds[CC * V];
  int tid = threadIdx.x;
  int tw = tid & 15, th = (tid >> 4) & 3, td = tid >> 6;
  int ntW = Do / TW, ntH = Do / TH, ntD = Do / TD;
  int bx = blockIdx.x;
  int w0 = (bx % ntW) * TW; bx /= ntW;
  int h0 = (bx % ntH) * TH; bx /= ntH;
  int d0 = (bx % ntD) * TD;
  int n  = bx / ntD;
  int co0 = blockIdx.y * CT;
  int Din = 2 * Do;
  long spi = (long)Din * Din * Din;
  long spo = (long)Do * Do * Do;
  const bf16* bIn = in + (long)n * Cin * spi;

  float acc[CT];
#pragma unroll
  for (int i = 0; i < CT; ++i) acc[i] = 0.f;

  int i0d = 2 * d0 - 1, i0h = 2 * h0 - 1, i0w = 2 * w0 - 1;
  for (int ci0 = 0; ci0 < Cin; ci0 += CC) {
    __syncthreads();
    for (int idx = tid; idx < CC * V; idx += TPB) {
      int cc = idx / V; int r = idx % V;
      int zd = r / (LH * LW); int rr = r % (LH * LW);
      int zh = rr / LW; int zw = rr % LW;
      int gd = i0d + zd, gh = i0h + zh, gw = i0w + zw;
      bf16 v = zval<bf16>();
      if ((unsigned)gd < (unsigned)Din && (unsigned)gh < (unsigned)Din && (unsigned)gw < (unsigned)Din)
        v = bIn[(long)(ci0 + cc) * spi + ((long)gd * Din + gh) * Din + gw];
      lds[idx] = v;
    }
    __syncthreads();
#pragma unroll 1
    for (int cc = 0; cc < CC; ++cc) {
      const bf16* base = lds + cc * V + (2 * td) * (LH * LW) + (2 * th) * LW + 2 * tw;
      const float* wci = wt + (long)(ci0 + cc) * Cout + co0;
#pragma unroll
      for (int kd = 0; kd < 3; ++kd) {
#pragma unroll
        for (int kh = 0; kh < 3; ++kh) {
          const bf16* row = base + kd * (LH * LW) + kh * LW;
          float v0 = toF(row[0]), v1 = toF(row[1]), v2 = toF(row[2]);
          long tb = (long)((kd * 3 + kh) * 3) * Cin * Cout;
          const float* wp0 = wci + tb;
          const float* wp1 = wp0 + (long)Cin * Cout;
          const float* wp2 = wp1 + (long)Cin * Cout;
#pragma unroll
          for (int co = 0; co < CT; ++co)
            acc[co] += v0 * wp0[co] + v1 * wp1[co] + v2 * wp2[co];
        }
      }
    }
  }
  long obase = ((long)n * Cout + co0) * spo + (((long)(d0 + td) * Do + (h0 + th)) * Do + (w0 + tw));
#pragma unroll
  for (int co = 0; co < CT; ++co) out[obase + (long)co * spo] = __float2bfloat16(acc[co]);
}

// ---------------- stride-2 tconv 'SAME', octant form, LDS-tiled ------------
// grid.z = octant (pd,ph,pw). Each block tiles the input half-grid 4x4x16,
// halo 1 on the low side only -> LDS (5,5,17) per ci. Weights [tap][ci][co].
template <int CT, int CC>
__global__ __launch_bounds__(TPB) void tconv_oct_t(
    const bf16* __restrict__ inA, int CA, const bf16* __restrict__ inB, int CB,
    const float* __restrict__ w, bf16* __restrict__ out,
    int N, int Cout, int Din) {
  const int TD = 4, TH = 4, TW = 16;
  const int LD = TD + 1, LH = TH + 1, LW = TW + 1;   // 5,5,17
  const int V = LD * LH * LW;                        // 425
  __shared__ bf16 lds[CC * V];
  int tid = threadIdx.x;
  int tw = tid & 15, th = (tid >> 4) & 3, td = tid >> 6;
  int ntW = Din / TW, ntH = Din / TH, ntD = Din / TD;
  int bx = blockIdx.x;
  int w0 = (bx % ntW) * TW; bx /= ntW;
  int h0 = (bx % ntH) * TH; bx /= ntH;
  int d0 = (bx % ntD) * TD;
  int n  = bx / ntD;
  int co0 = blockIdx.y * CT;
  int oct = blockIdx.z;
  int pd = (oct >> 2) & 1, ph = (oct >> 1) & 1, pw = oct & 1;
  int Cin = CA + CB;
  long spi = (long)Din * Din * Din;
  int Dout = 2 * Din;
  long spo = (long)Dout * Dout * Dout;
  const bf16* bA = inA + (long)n * CA * spi;
  const bf16* bB = inB ? inB + (long)n * CB * spi : nullptr;

  // per-dim tap lists: parity 1 -> {k=1,delta=0}; parity 0 -> {k=0,d=-1},{k=2,d=0}
  int nkd, kds[2], dds[2];
  if (pd) { nkd = 1; kds[0] = 1; dds[0] = 0; } else { nkd = 2; kds[0] = 0; dds[0] = -1; kds[1] = 2; dds[1] = 0; }
  int nkh, khs[2], dhs[2];
  if (ph) { nkh = 1; khs[0] = 1; dhs[0] = 0; } else { nkh = 2; khs[0] = 0; dhs[0] = -1; khs[1] = 2; dhs[1] = 0; }
  int nkw, kws[2], dws[2];
  if (pw) { nkw = 1; kws[0] = 1; dws[0] = 0; } else { nkw = 2; kws[0] = 0; dws[0] = -1; kws[1] = 2; dws[1] = 0; }

  float acc[CT];
#pragma unroll
  for (int i = 0; i < CT; ++i) acc[i] = 0.f;

  for (int ci0 = 0; ci0 < Cin; ci0 += CC) {
    __syncthreads();
    for (int idx = tid; idx < CC * V; idx += TPB) {
      int cc = idx / V; int r = idx % V;
      int zd = r / (LH * LW); int rr = r % (LH * LW);
      int zh = rr / LW; int zw = rr % LW;
      int gd = d0 + zd - 1, gh = h0 + zh - 1, gw = w0 + zw - 1;
      bf16 v = zval<bf16>();
      if ((unsigned)gd < (unsigned)Din && (unsigned)gh < (unsigned)Din && (unsigned)gw < (unsigned)Din) {
        int ci = ci0 + cc;
        long off = ((long)gd * Din + gh) * Din + gw;
        v = (ci < CA) ? bA[(long)ci * spi + off] : bB[(long)(ci - CA) * spi + off];
      }
      lds[idx] = v;
    }
    __syncthreads();
#pragma unroll 1
    for (int cc = 0; cc < CC; ++cc) {
      const bf16* base = lds + cc * V;
      const float* wci = w + (long)(ci0 + cc) * Cout + co0;
      for (int a = 0; a < nkd; ++a) {
        int zd = td + 1 + dds[a];
        for (int b = 0; b < nkh; ++b) {
          int zh = th + 1 + dhs[b];
          for (int c = 0; c < nkw; ++c) {
            int zw = tw + 1 + dws[c];
            int tap = (kds[a] * 3 + khs[b]) * 3 + kws[c];
            float v = toF(base[(zd * LH + zh) * LW + zw]);
            const float* wp = wci + (long)tap * Cin * Cout;
#pragma unroll
            for (int co = 0; co < CT; ++co) acc[co] += v * wp[co];
          }
        }
      }
    }
  }
  int od = 2 * (d0 + td) + pd, oh = 2 * (h0 + th) + ph, ow = 2 * (w0 + tw) + pw;
  long obase = ((long)n * Cout + co0) * spo + (((long)od * Dout + oh) * Dout + ow);
#pragma unroll
  for (int co = 0; co < CT; ++co) out[obase + (long)co * spo] = __float2bfloat16(acc[co]);
}

// ---------------- BN stats stage 1: per (channel, chunk) partial sums ------
__global__ void bn_stats1_k(const unsigned short* __restrict__ x, float* __restrict__ part,
                            int N, int C, long sp, int lsp, int K) {
  int c = blockIdx.x, ch = blockIdx.y, tid = threadIdx.x;
  long tot = (long)N * sp;
  float s = 0.f, q = 0.f;
  for (long e = ((long)ch * TPB + tid) * 8; e < tot; e += (long)K * TPB * 8) {
    int n = (int)(e >> lsp);
    long i = e & (sp - 1);
    const ushort8 vv = *(const ushort8*)(x + ((long)n * C + c) * sp + i);
#pragma unroll
    for (int j = 0; j < 8; ++j) { float f = b2f(vv[j]); s += f; q += f * f; }
  }
  __shared__ float shs[TPB], shq[TPB];
  shs[tid] = s; shq[tid] = q;
  __syncthreads();
  for (int off = TPB / 2; off > 0; off >>= 1) {
    if (tid < off) { shs[tid] += shs[tid + off]; shq[tid] += shq[tid + off]; }
    __syncthreads();
  }
  if (tid == 0) { part[((long)c * K + ch) * 2] = shs[0]; part[((long)c * K + ch) * 2 + 1] = shq[0]; }
}

// ---------------- BN stats stage 2: reduce partials -> scale/shift ---------
__global__ void bn_stats2_k(const float* __restrict__ part, const float* __restrict__ g,
                            const float* __restrict__ b, float* __restrict__ scale,
                            float* __restrict__ shift, int C, int K, float inv_cnt) {
  int c = blockIdx.x * blockDim.x + threadIdx.x;
  if (c >= C) return;
  float s = 0.f, q = 0.f;
  for (int k = 0; k < K; ++k) { s += part[((long)c * K + k) * 2]; q += part[((long)c * K + k) * 2 + 1]; }
  float m = s * inv_cnt, v = q * inv_cnt - m * m;
  float rs = rsqrtf(v + 1e-5f) * g[c];
  scale[c] = rs;
  shift[c] = b[c] - m * rs;
}

// ---------------- BN apply + ReLU (vectorized, in place) -------------------
__global__ void bn_relu_k(unsigned short* __restrict__ x, const float* __restrict__ scale,
                          const float* __restrict__ shift, int C, int lsp, long tot8) {
  long i8 = (long)blockIdx.x * blockDim.x + threadIdx.x;
  if (i8 >= tot8) return;
  long e = i8 * 8;
  int c = (int)((e >> lsp) % C);
  float sc = scale[c], sh = shift[c];
  ushort8 v = *(ushort8*)(x + e);
  ushort8 r;
#pragma unroll
  for (int j = 0; j < 8; ++j) {
    float y = b2f(v[j]) * sc + sh;
    r[j] = f2b(y > 0.f ? y : 0.f);
  }
  *(ushort8*)(x + e) = r;
}

extern "C" void kernel_launch(void* const* d_in, const int* in_sizes, int n_in,
                              void* d_out, int out_size, void* d_ws, size_t ws_size,
                              hipStream_t stream) {
  const float* x    = (const float*)d_in[0];
  const float* w0   = (const float*)d_in[1];
  const float* g0   = (const float*)d_in[2];
  const float* b0   = (const float*)d_in[3];
  const float* w1   = (const float*)d_in[4];
  const float* g1   = (const float*)d_in[5];
  const float* b1   = (const float*)d_in[6];
  const float* w2   = (const float*)d_in[7];
  const float* g2   = (const float*)d_in[8];
  const float* b2   = (const float*)d_in[9];
  const float* wt2r = (const float*)d_in[10];
  const float* g2r  = (const float*)d_in[11];
  const float* b2r  = (const float*)d_in[12];
  const float* wt1r = (const float*)d_in[13];
  const float* g1r  = (const float*)d_in[14];
  const float* b1r  = (const float*)d_in[15];
  const float* wt0r = (const float*)d_in[16];
  const float* wt2c = (const float*)d_in[17];
  const float* g2c  = (const float*)d_in[18];
  const float* b2c  = (const float*)d_in[19];
  const float* wt1c = (const float*)d_in[20];
  const float* g1c  = (const float*)d_in[21];
  const float* b1c  = (const float*)d_in[22];
  const float* wt0c = (const float*)d_in[23];

  const int N = 2;
  const long sp64 = 64L * 64 * 64, sp32 = 32L * 32 * 32, sp16 = 16L * 16 * 16;
  const int K = 8;  // bn chunks

  // ---- workspace layout ----
  bf16* s1  = (bf16*)d_ws;                  // 16,777,216 el
  bf16* s2  = s1  + 2L * 32 * sp64;         //  4,194,304
  bf16* s4  = s2  + 2L * 64 * sp32;         //  1,048,576
  bf16* r32 = s4  + 2L * 128 * sp16;        //  4,194,304
  bf16* c32 = r32 + 2L * 64 * sp32;         //  4,194,304
  bf16* r64 = c32 + 2L * 64 * sp32;         // 16,777,216
  bf16* c64 = r64 + 2L * 32 * sp64;         // 33,554,432
  float* wtp0 = (float*)(c64 + 2L * 64 * sp64);  // 27*16*32
  float* wtp1 = wtp0 + 27L * 16 * 32;            // 27*32*64
  float* wtp2 = wtp1 + 27L * 32 * 64;            // 27*64*128
  float* part = wtp2 + 27L * 64 * 128;           // 128*K*2
  float* bsc  = part + 128L * K * 2;
  float* bsh  = bsc + 128;

  float* out_cl  = (float*)d_out;
  float* out_rec = (float*)d_out + 2L * 2 * sp64;

  // ---- repack encoder weights to [tap][ci][co] ----
  repack_k<<<cdiv_l(27L * 16 * 32, TPB), TPB, 0, stream>>>(w0, wtp0, 16, 32);
  repack_k<<<cdiv_l(27L * 32 * 64, TPB), TPB, 0, stream>>>(w1, wtp1, 32, 64);
  repack_k<<<cdiv_l(27L * 64 * 128, TPB), TPB, 0, stream>>>(w2, wtp2, 64, 128);

  auto bn = [&](bf16* tens, const float* g, const float* b, int C, long sp, int lsp) {
    bn_stats1_k<<<dim3((unsigned)C, K), TPB, 0, stream>>>((unsigned short*)tens, part, N, C, sp, lsp, K);
    bn_stats2_k<<<1, 128, 0, stream>>>(part, g, b, bsc, bsh, C, K, 1.f / (float)(N * sp));
    long tot8 = (long)N * C * sp / 8;
    bn_relu_k<<<cdiv_l(tot8, TPB), TPB, 0, stream>>>((unsigned short*)tens, bsc, bsh, C, lsp, tot8);
  };

  // ---- encoder ----
  // conv0: 16->32, 64^3, stride 1. tiles: 2 * (16*16*4) = 2048
  conv_s1_t<float, bf16, 32, 8><<<dim3(2048, 1), TPB, 0, stream>>>(x, 16, nullptr, 0, wtp0, s1, N, 32, 64);
  bn(s1, g0, b0, 32, sp64, 18);
  // conv1: 32->64, 64^3 -> 32^3. tiles: 2 * (8*8*2) = 256, y=2
  conv_s2_t<32, 4><<<dim3(256, 2), TPB, 0, stream>>>(s1, wtp1, s2, N, 32, 64, 32);
  bn(s2, g1, b1, 64, sp32, 15);
  // conv2: 64->128, 32^3 -> 16^3. tiles: 2 * (4*4*1) = 32, y=8
  conv_s2_t<16, 4><<<dim3(32, 8), TPB, 0, stream>>>(s2, wtp2, s4, N, 64, 128, 16);
  bn(s4, g2, b2, 128, sp16, 12);

  // ---- level-2 tconvs (16 -> 32) ----
  tconv_oct_t<32, 8><<<dim3(32, 2, 8), TPB, 0, stream>>>(s4, 128, nullptr, 0, wt2r, r32, N, 64, 16);
  bn(r32, g2r, b2r, 64, sp32, 15);
  tconv_oct_t<32, 8><<<dim3(32, 2, 8), TPB, 0, stream>>>(s4, 128, nullptr, 0, wt2c, c32, N, 64, 16);
  bn(c32, g2c, b2c, 64, sp32, 15);

  // ---- level-1 tconvs (32 -> 64) ----
  tconv_oct_t<32, 8><<<dim3(256, 1, 8), TPB, 0, stream>>>(r32, 64, nullptr, 0, wt1r, r64, N, 32, 32);
  bn(r64, g1r, b1r, 32, sp64, 18);
  tconv_oct_t<32, 8><<<dim3(256, 2, 8), TPB, 0, stream>>>(c32, 64, s2, 64, wt1c, c64, N, 64, 32);
  bn(c64, g1c, b1c, 64, sp64, 18);

  // ---- level-0 tconvs (stride 1, no BN) -> fp32 outputs ----
  conv_s1_t<bf16, float, 16, 8><<<dim3(2048, 1), TPB, 0, stream>>>(r64, 32, nullptr, 0, wt0r, out_rec, N, 16, 64);
  conv_s1_t<bf16, float, 2, 8><<<dim3(2048, 1), TPB, 0, stream>>>(c64, 64, s1, 32, wt0c, out_cl, N, 2, 64);
}

// Round 5
// 3667.784 us; speedup vs baseline: 1.0586x; 1.0586x over previous
//
#include <hip/hip_runtime.h>
#include <hip/hip_bf16.h>

// ---------------------------------------------------------------------------
// UNet3D dense forward, round 5: implicit-GEMM MFMA (bf16) for tap-decomposed
// convs/tconvs; encoder stride-2 convs stay on the VALU path.
//  - mfma_f32_16x16x32_bf16: M=16 co, N=16 spatial(w-run), K=32 ci.
//  - LDS tile [6][6][18] points x [ci 32 (pad 40)] -> B-frags via ds_read_b128.
//  - weights repacked bf16 [tap][co][ci] (zero-padded) -> A-frags via global b128.
//  - octant tconv: per-octant uniform tap lists (verified R3/R4).
// ---------------------------------------------------------------------------

using bf16 = __hip_bfloat16;
using ushort8 = __attribute__((ext_vector_type(8))) unsigned short;
using short8  = __attribute__((ext_vector_type(8))) short;
using f32x4   = __attribute__((ext_vector_type(4))) float;

#define TPB 256

static inline int cdiv_l(long a, int b){ return (int)((a + b - 1) / b); }

__device__ __forceinline__ float b2f(unsigned short u){
  union { unsigned int i; float f; } v; v.i = ((unsigned int)u) << 16; return v.f;
}
__device__ __forceinline__ unsigned short f2b(float f){
  union { bf16 h; unsigned short u; } v; v.h = __float2bfloat16(f); return v.u;
}
__device__ __forceinline__ unsigned short ldbf(const float* p){ return f2b(*p); }
__device__ __forceinline__ unsigned short ldbf(const bf16* p){ return *(const unsigned short*)p; }
__device__ __forceinline__ void stOut(float* p, float v){ *p = v; }
__device__ __forceinline__ void stOut(bf16* p, float v){ *p = __float2bfloat16(v); }

// ---------------- weight repacks ----------------
// OIDHW fp32 -> fp32 [tap][ci][co]   (VALU stride-2 conv path)
__global__ void repack_k(const float* __restrict__ w, float* __restrict__ wt,
                         int Cin, int Cout){
  int idx = blockIdx.x * blockDim.x + threadIdx.x;
  int tot = 27 * Cin * Cout;
  if (idx >= tot) return;
  int co = idx % Cout; int t = idx / Cout;
  int ci = t % Cin;    int tap = t / Cin;
  wt[idx] = w[((long)co * Cin + ci) * 27 + tap];
}
// OIDHW fp32 -> bf16 [tap][COP][CIP], zero-padded   (MFMA path, encoder)
__global__ void repack_mfma_enc(const float* __restrict__ w, unsigned short* __restrict__ wb,
                                int Cin, int Cout, int CIP, int COP){
  int idx = blockIdx.x * blockDim.x + threadIdx.x;
  int tot = 27 * COP * CIP;
  if (idx >= tot) return;
  int ci = idx % CIP; int t = idx / CIP; int co = t % COP; int tap = t / COP;
  float v = (ci < Cin && co < Cout) ? w[((long)co * Cin + ci) * 27 + tap] : 0.f;
  wb[idx] = f2b(v);
}
// DHWIO fp32 -> bf16 [tap][COP][CIP], zero-padded   (MFMA path, decoder)
__global__ void repack_mfma_dec(const float* __restrict__ w, unsigned short* __restrict__ wb,
                                int Cin, int Cout, int CIP, int COP){
  int idx = blockIdx.x * blockDim.x + threadIdx.x;
  int tot = 27 * COP * CIP;
  if (idx >= tot) return;
  int ci = idx % CIP; int t = idx / CIP; int co = t % COP; int tap = t / COP;
  float v = (ci < Cin && co < Cout) ? w[((long)tap * Cin + ci) * Cout + co] : 0.f;
  wb[idx] = f2b(v);
}

// ---------------- unified MFMA tap-GEMM conv ----------------
// VARIANT 0: stride-1 conv pad 1 (27 taps, out grid == in grid G).
// VARIANT 1: stride-2 tconv octant (blockIdx.z = octant, out grid == 2G).
// Block: 4(d) x 4(h) x 16(w) tile on the input/out grid; 4 waves; wave wv owns
// d-slice wv, computing a 16co x 16w MFMA tile for each of 4 h rows.
template <int VARIANT, typename Tin, typename Tout>
__global__ __launch_bounds__(TPB) void mfma_conv_k(
    const Tin* __restrict__ inA, int CA, const Tin* __restrict__ inB, int CB,
    const unsigned short* __restrict__ wb, Tout* __restrict__ out,
    int N, int Cout, int COP, int CIP, int G) {
  __shared__ __align__(16) unsigned short xs[648 * 40];   // [6*6*18 pts][ci 32 pad 40]
  const int tid = threadIdx.x;
  const int wv = tid >> 6, l = tid & 63;
  const int l15 = l & 15, lg = l >> 4;
  int ntW = G >> 4, ntH = G >> 2, ntD = G >> 2;
  int bx = blockIdx.x;
  int w0 = (bx % ntW) << 4; bx /= ntW;
  int h0 = (bx % ntH) << 2; bx /= ntH;
  int d0 = (bx % ntD) << 2; int n = bx / ntD;
  int co0 = blockIdx.y << 4;
  long sp = (long)G * G * G;

  int nkd, kds[3], dds[3], nkh, khs[3], dhs[3], nkw, kws[3], dws[3];
  int pd = 0, ph = 0, pw = 0;
  if (VARIANT == 0) {
    nkd = nkh = nkw = 3;
    kds[0]=0; kds[1]=1; kds[2]=2;  dds[0]=-1; dds[1]=0; dds[2]=1;
    khs[0]=0; khs[1]=1; khs[2]=2;  dhs[0]=-1; dhs[1]=0; dhs[2]=1;
    kws[0]=0; kws[1]=1; kws[2]=2;  dws[0]=-1; dws[1]=0; dws[2]=1;
  } else {
    int oct = blockIdx.z;
    pd = (oct >> 2) & 1; ph = (oct >> 1) & 1; pw = oct & 1;
    if (pd){ nkd=1; kds[0]=1; dds[0]=0; } else { nkd=2; kds[0]=0; dds[0]=-1; kds[1]=2; dds[1]=0; }
    if (ph){ nkh=1; khs[0]=1; dhs[0]=0; } else { nkh=2; khs[0]=0; dhs[0]=-1; khs[1]=2; dhs[1]=0; }
    if (pw){ nkw=1; kws[0]=1; dws[0]=0; } else { nkw=2; kws[0]=0; dws[0]=-1; kws[1]=2; dws[1]=0; }
  }

  f32x4 acc[4];
#pragma unroll
  for (int j = 0; j < 4; ++j) acc[j] = (f32x4){0.f, 0.f, 0.f, 0.f};

  const int Creal = CA + CB;
  for (int c0 = 0; c0 < CIP; c0 += 32) {
    __syncthreads();
#pragma unroll 1
    for (int idx = tid; idx < 20736; idx += TPB) {   // 648 pts * 32 ci
      int pt = idx % 648; int cil = idx / 648;
      int zw = pt % 18; int zt = pt / 18; int zh = zt % 6; int zd = zt / 6;
      int gd = d0 + zd - 1, gh = h0 + zh - 1, gw = w0 + zw - 1;
      int ci = c0 + cil;
      unsigned short v = 0;
      if ((unsigned)gd < (unsigned)G && (unsigned)gh < (unsigned)G &&
          (unsigned)gw < (unsigned)G && ci < Creal) {
        long off = ((long)gd * G + gh) * G + gw;
        v = (ci < CA) ? ldbf(inA + ((long)n * CA + ci) * sp + off)
                      : ldbf(inB + ((long)n * CB + (ci - CA)) * sp + off);
      }
      xs[pt * 40 + cil] = v;
    }
    __syncthreads();

    for (int a = 0; a < nkd; ++a) {
      int zd = wv + 1 + dds[a];
      for (int b = 0; b < nkh; ++b) {
        for (int c = 0; c < nkw; ++c) {
          int tap = (kds[a] * 3 + khs[b]) * 3 + kws[c];
          const unsigned short* ap = wb + ((long)tap * COP + co0 + l15) * CIP + c0 + lg * 8;
          short8 A = *(const short8*)ap;
          int zb = ((zd * 6 + 1 + dhs[b]) * 18 + l15 + 1 + dws[c]) * 40 + lg * 8;
#pragma unroll
          for (int j = 0; j < 4; ++j) {
            short8 B = *(const short8*)(xs + zb + j * (18 * 40));
            acc[j] = __builtin_amdgcn_mfma_f32_16x16x32_bf16(A, B, acc[j], 0, 0, 0);
          }
        }
      }
    }
  }

  if (VARIANT == 0) {
#pragma unroll
    for (int j = 0; j < 4; ++j) {
      int od = d0 + wv, oh = h0 + j, ow = w0 + l15;
      long pbase = ((long)od * G + oh) * G + ow;
#pragma unroll
      for (int r = 0; r < 4; ++r) {
        int co = co0 + lg * 4 + r;
        if (co < Cout) stOut(out + ((long)n * Cout + co) * sp + pbase, acc[j][r]);
      }
    }
  } else {
    int Gout = 2 * G; long spo = (long)Gout * Gout * Gout;
#pragma unroll
    for (int j = 0; j < 4; ++j) {
      int od = 2 * (d0 + wv) + pd, oh = 2 * (h0 + j) + ph, ow = 2 * (w0 + l15) + pw;
      long pbase = ((long)od * Gout + oh) * Gout + ow;
#pragma unroll
      for (int r = 0; r < 4; ++r) {
        int co = co0 + lg * 4 + r;
        if (co < Cout) stOut(out + ((long)n * Cout + co) * spo + pbase, acc[j][r]);
      }
    }
  }
}

// ---------------- stride-2 3x3x3 conv pad 1, LDS-tiled (VALU, from R4) ------
template <int CT, int CC>
__global__ __launch_bounds__(TPB) void conv_s2_t(
    const bf16* __restrict__ in, const float* __restrict__ wt, bf16* __restrict__ out,
    int N, int Cin, int Cout, int Do) {
  const int TD = 4, TH = 4, TW = 16;
  const int LD = 2 * TD + 1, LH = 2 * TH + 1, LW = 2 * TW + 1;  // 9,9,33
  const int V = LD * LH * LW;                                    // 2673
  __shared__ bf16 lds[CC * V];
  int tid = threadIdx.x;
  int tw = tid & 15, th = (tid >> 4) & 3, td = tid >> 6;
  int ntW = Do / TW, ntH = Do / TH, ntD = Do / TD;
  int bx = blockIdx.x;
  int w0 = (bx % ntW) * TW; bx /= ntW;
  int h0 = (bx % ntH) * TH; bx /= ntH;
  int d0 = (bx % ntD) * TD;
  int n  = bx / ntD;
  int co0 = blockIdx.y * CT;
  int Din = 2 * Do;
  long spi = (long)Din * Din * Din;
  long spo = (long)Do * Do * Do;
  const bf16* bIn = in + (long)n * Cin * spi;

  float acc[CT];
#pragma unroll
  for (int i = 0; i < CT; ++i) acc[i] = 0.f;

  int i0d = 2 * d0 - 1, i0h = 2 * h0 - 1, i0w = 2 * w0 - 1;
  for (int ci0 = 0; ci0 < Cin; ci0 += CC) {
    __syncthreads();
    for (int idx = tid; idx < CC * V; idx += TPB) {
      int cc = idx / V; int r = idx % V;
      int zd = r / (LH * LW); int rr = r % (LH * LW);
      int zh = rr / LW; int zw = rr % LW;
      int gd = i0d + zd, gh = i0h + zh, gw = i0w + zw;
      bf16 v = __float2bfloat16(0.f);
      if ((unsigned)gd < (unsigned)Din && (unsigned)gh < (unsigned)Din && (unsigned)gw < (unsigned)Din)
        v = bIn[(long)(ci0 + cc) * spi + ((long)gd * Din + gh) * Din + gw];
      lds[idx] = v;
    }
    __syncthreads();
#pragma unroll 1
    for (int cc = 0; cc < CC; ++cc) {
      const bf16* base = lds + cc * V + (2 * td) * (LH * LW) + (2 * th) * LW + 2 * tw;
      const float* wci = wt + (long)(ci0 + cc) * Cout + co0;
#pragma unroll
      for (int kd = 0; kd < 3; ++kd) {
#pragma unroll
        for (int kh = 0; kh < 3; ++kh) {
          const bf16* row = base + kd * (LH * LW) + kh * LW;
          float v0 = __bfloat162float(row[0]), v1 = __bfloat162float(row[1]), v2 = __bfloat162float(row[2]);
          long tb = (long)((kd * 3 + kh) * 3) * Cin * Cout;
          const float* wp0 = wci + tb;
          const float* wp1 = wp0 + (long)Cin * Cout;
          const float* wp2 = wp1 + (long)Cin * Cout;
#pragma unroll
          for (int co = 0; co < CT; ++co)
            acc[co] += v0 * wp0[co] + v1 * wp1[co] + v2 * wp2[co];
        }
      }
    }
  }
  long obase = ((long)n * Cout + co0) * spo + (((long)(d0 + td) * Do + (h0 + th)) * Do + (w0 + tw));
#pragma unroll
  for (int co = 0; co < CT; ++co) out[obase + (long)co * spo] = __float2bfloat16(acc[co]);
}

// ---------------- BN stats stage 1: per (channel, chunk) partial sums ------
__global__ void bn_stats1_k(const unsigned short* __restrict__ x, float* __restrict__ part,
                            int N, int C, long sp, int lsp, int K) {
  int c = blockIdx.x, ch = blockIdx.y, tid = threadIdx.x;
  long tot = (long)N * sp;
  float s = 0.f, q = 0.f;
  for (long e = ((long)ch * TPB + tid) * 8; e < tot; e += (long)K * TPB * 8) {
    int n = (int)(e >> lsp);
    long i = e & (sp - 1);
    const ushort8 vv = *(const ushort8*)(x + ((long)n * C + c) * sp + i);
#pragma unroll
    for (int j = 0; j < 8; ++j) { float f = b2f(vv[j]); s += f; q += f * f; }
  }
  __shared__ float shs[TPB], shq[TPB];
  shs[tid] = s; shq[tid] = q;
  __syncthreads();
  for (int off = TPB / 2; off > 0; off >>= 1) {
    if (tid < off) { shs[tid] += shs[tid + off]; shq[tid] += shq[tid + off]; }
    __syncthreads();
  }
  if (tid == 0) { part[((long)c * K + ch) * 2] = shs[0]; part[((long)c * K + ch) * 2 + 1] = shq[0]; }
}

// ---------------- BN stats stage 2 ----------------
__global__ void bn_stats2_k(const float* __restrict__ part, const float* __restrict__ g,
                            const float* __restrict__ b, float* __restrict__ scale,
                            float* __restrict__ shift, int C, int K, float inv_cnt) {
  int c = blockIdx.x * blockDim.x + threadIdx.x;
  if (c >= C) return;
  float s = 0.f, q = 0.f;
  for (int k = 0; k < K; ++k) { s += part[((long)c * K + k) * 2]; q += part[((long)c * K + k) * 2 + 1]; }
  float m = s * inv_cnt, v = q * inv_cnt - m * m;
  float rs = rsqrtf(v + 1e-5f) * g[c];
  scale[c] = rs;
  shift[c] = b[c] - m * rs;
}

// ---------------- BN apply + ReLU (vectorized, in place) -------------------
__global__ void bn_relu_k(unsigned short* __restrict__ x, const float* __restrict__ scale,
                          const float* __restrict__ shift, int C, int lsp, long tot8) {
  long i8 = (long)blockIdx.x * blockDim.x + threadIdx.x;
  if (i8 >= tot8) return;
  long e = i8 * 8;
  int c = (int)((e >> lsp) % C);
  float sc = scale[c], sh = shift[c];
  ushort8 v = *(ushort8*)(x + e);
  ushort8 r;
#pragma unroll
  for (int j = 0; j < 8; ++j) {
    float y = b2f(v[j]) * sc + sh;
    r[j] = f2b(y > 0.f ? y : 0.f);
  }
  *(ushort8*)(x + e) = r;
}

extern "C" void kernel_launch(void* const* d_in, const int* in_sizes, int n_in,
                              void* d_out, int out_size, void* d_ws, size_t ws_size,
                              hipStream_t stream) {
  const float* x    = (const float*)d_in[0];
  const float* w0   = (const float*)d_in[1];
  const float* g0   = (const float*)d_in[2];
  const float* b0   = (const float*)d_in[3];
  const float* w1   = (const float*)d_in[4];
  const float* g1   = (const float*)d_in[5];
  const float* b1   = (const float*)d_in[6];
  const float* w2   = (const float*)d_in[7];
  const float* g2   = (const float*)d_in[8];
  const float* b2   = (const float*)d_in[9];
  const float* wt2r = (const float*)d_in[10];
  const float* g2r  = (const float*)d_in[11];
  const float* b2r  = (const float*)d_in[12];
  const float* wt1r = (const float*)d_in[13];
  const float* g1r  = (const float*)d_in[14];
  const float* b1r  = (const float*)d_in[15];
  const float* wt0r = (const float*)d_in[16];
  const float* wt2c = (const float*)d_in[17];
  const float* g2c  = (const float*)d_in[18];
  const float* b2c  = (const float*)d_in[19];
  const float* wt1c = (const float*)d_in[20];
  const float* g1c  = (const float*)d_in[21];
  const float* b1c  = (const float*)d_in[22];
  const float* wt0c = (const float*)d_in[23];

  const int N = 2;
  const long sp64 = 64L * 64 * 64, sp32 = 32L * 32 * 32, sp16 = 16L * 16 * 16;
  const int K = 8;  // bn chunks

  // ---- workspace layout ----
  bf16* s1  = (bf16*)d_ws;                  // 16,777,216 el
  bf16* s2  = s1  + 2L * 32 * sp64;         //  4,194,304
  bf16* s4  = s2  + 2L * 64 * sp32;         //  1,048,576
  bf16* r32 = s4  + 2L * 128 * sp16;        //  4,194,304
  bf16* c32 = r32 + 2L * 64 * sp32;         //  4,194,304
  bf16* r64 = c32 + 2L * 64 * sp32;         // 16,777,216
  bf16* c64 = r64 + 2L * 32 * sp64;         // 33,554,432
  unsigned short* wb0  = (unsigned short*)(c64 + 2L * 64 * sp64); // 27*32*32
  unsigned short* wb2r = wb0  + 27L * 32 * 32;   // 27*64*128
  unsigned short* wb2c = wb2r + 27L * 64 * 128;
  unsigned short* wb1r = wb2c + 27L * 64 * 128;  // 27*32*64
  unsigned short* wb1c = wb1r + 27L * 32 * 64;   // 27*64*128
  unsigned short* wbrec= wb1c + 27L * 64 * 128;  // 27*16*32
  unsigned short* wbcl = wbrec+ 27L * 16 * 32;   // 27*16*96
  float* wtp1 = (float*)(wbcl + 27L * 16 * 96);  // 27*32*64 f32
  float* wtp2 = wtp1 + 27L * 32 * 64;            // 27*64*128 f32
  float* part = wtp2 + 27L * 64 * 128;           // 128*K*2
  float* bsc  = part + 128L * K * 2;
  float* bsh  = bsc + 128;

  float* out_cl  = (float*)d_out;
  float* out_rec = (float*)d_out + 2L * 2 * sp64;

  // ---- weight repacks ----
  repack_mfma_enc<<<cdiv_l(27L*32*32, TPB), TPB, 0, stream>>>(w0, wb0, 16, 32, 32, 32);
  repack_k<<<cdiv_l(27L*32*64, TPB), TPB, 0, stream>>>(w1, wtp1, 32, 64);
  repack_k<<<cdiv_l(27L*64*128, TPB), TPB, 0, stream>>>(w2, wtp2, 64, 128);
  repack_mfma_dec<<<cdiv_l(27L*64*128, TPB), TPB, 0, stream>>>(wt2r, wb2r, 128, 64, 128, 64);
  repack_mfma_dec<<<cdiv_l(27L*64*128, TPB), TPB, 0, stream>>>(wt2c, wb2c, 128, 64, 128, 64);
  repack_mfma_dec<<<cdiv_l(27L*32*64, TPB), TPB, 0, stream>>>(wt1r, wb1r, 64, 32, 64, 32);
  repack_mfma_dec<<<cdiv_l(27L*64*128, TPB), TPB, 0, stream>>>(wt1c, wb1c, 128, 64, 128, 64);
  repack_mfma_dec<<<cdiv_l(27L*16*32, TPB), TPB, 0, stream>>>(wt0r, wbrec, 32, 16, 32, 16);
  repack_mfma_dec<<<cdiv_l(27L*16*96, TPB), TPB, 0, stream>>>(wt0c, wbcl, 96, 2, 96, 16);

  auto bn = [&](bf16* tens, const float* g, const float* b, int C, long sp, int lsp) {
    bn_stats1_k<<<dim3((unsigned)C, K), TPB, 0, stream>>>((unsigned short*)tens, part, N, C, sp, lsp, K);
    bn_stats2_k<<<1, 128, 0, stream>>>(part, g, b, bsc, bsh, C, K, 1.f / (float)(N * sp));
    long tot8 = (long)N * C * sp / 8;
    bn_relu_k<<<cdiv_l(tot8, TPB), TPB, 0, stream>>>((unsigned short*)tens, bsc, bsh, C, lsp, tot8);
  };

  // ---- encoder ----
  // conv0 (MFMA): 16->32, 64^3, stride 1
  mfma_conv_k<0, float, bf16><<<dim3(2048, 2), TPB, 0, stream>>>(
      x, 16, (const float*)nullptr, 0, wb0, s1, N, 32, 32, 32, 64);
  bn(s1, g0, b0, 32, sp64, 18);
  // conv1 (VALU): 32->64, 64^3 -> 32^3
  conv_s2_t<32, 4><<<dim3(256, 2), TPB, 0, stream>>>(s1, wtp1, s2, N, 32, 64, 32);
  bn(s2, g1, b1, 64, sp32, 15);
  // conv2 (VALU): 64->128, 32^3 -> 16^3
  conv_s2_t<16, 4><<<dim3(32, 8), TPB, 0, stream>>>(s2, wtp2, s4, N, 64, 128, 16);
  bn(s4, g2, b2, 128, sp16, 12);

  // ---- level-2 tconvs (16 -> 32), MFMA octant ----
  mfma_conv_k<1, bf16, bf16><<<dim3(32, 4, 8), TPB, 0, stream>>>(
      s4, 128, (const bf16*)nullptr, 0, wb2r, r32, N, 64, 64, 128, 16);
  bn(r32, g2r, b2r, 64, sp32, 15);
  mfma_conv_k<1, bf16, bf16><<<dim3(32, 4, 8), TPB, 0, stream>>>(
      s4, 128, (const bf16*)nullptr, 0, wb2c, c32, N, 64, 64, 128, 16);
  bn(c32, g2c, b2c, 64, sp32, 15);

  // ---- level-1 tconvs (32 -> 64), MFMA octant ----
  mfma_conv_k<1, bf16, bf16><<<dim3(256, 2, 8), TPB, 0, stream>>>(
      r32, 64, (const bf16*)nullptr, 0, wb1r, r64, N, 32, 32, 64, 32);
  bn(r64, g1r, b1r, 32, sp64, 18);
  mfma_conv_k<1, bf16, bf16><<<dim3(256, 4, 8), TPB, 0, stream>>>(
      c32, 64, s2, 64, wb1c, c64, N, 64, 64, 128, 32);
  bn(c64, g1c, b1c, 64, sp64, 18);

  // ---- level-0 tconvs (stride 1, no BN), MFMA -> fp32 outputs ----
  mfma_conv_k<0, bf16, float><<<dim3(2048, 1), TPB, 0, stream>>>(
      r64, 32, (const bf16*)nullptr, 0, wbrec, out_rec, N, 16, 16, 32, 64);
  mfma_conv_k<0, bf16, float><<<dim3(2048, 1), TPB, 0, stream>>>(
      c64, 64, s1, 32, wbcl, out_cl, N, 2, 16, 96, 64);
}

// Round 6
// 1692.548 us; speedup vs baseline: 2.2941x; 2.1670x over previous
//
#include <hip/hip_runtime.h>
#include <hip/hip_bf16.h>

// ---------------------------------------------------------------------------
// UNet3D dense forward, round 6: channels-last (NDHWC) implicit-GEMM MFMA,
// ZERO LDS staging. B-fragments (8 consecutive ci at a point) are direct 16B
// global loads served by L1/L2 across the 27 tap shifts; A-fragments are 16B
// loads of bf16 weights repacked [tap][co][ci]. One unified kernel handles
// stride-1 conv, stride-2 conv, and octant-decomposed stride-2 tconv.
// conv0 (Cin=16) packs 2 taps per K=32 MFMA. BN two-stage, channels-last.
// ---------------------------------------------------------------------------

using bf16 = __hip_bfloat16;
using ushort4v = __attribute__((ext_vector_type(4))) unsigned short;
using ushort8  = __attribute__((ext_vector_type(8))) unsigned short;
using short8   = __attribute__((ext_vector_type(8))) short;
using f32x4    = __attribute__((ext_vector_type(4))) float;
using float4v  = __attribute__((ext_vector_type(4))) float;

#define TPB 256

static inline int cdiv_l(long a, int b){ return (int)((a + b - 1) / b); }

__device__ __forceinline__ float b2f(unsigned short u){
  union { unsigned int i; float f; } v; v.i = ((unsigned int)u) << 16; return v.f;
}
__device__ __forceinline__ unsigned short f2b(float f){
  union { bf16 h; unsigned short u; } v; v.h = __float2bfloat16(f); return v.u;
}

// ---------------- weight repacks (bf16) ----------------
// OIDHW fp32 -> [tap][Cout][Cin] (encoder stride-2 convs; exact sizes)
__global__ void rp_enc(const float* __restrict__ w, unsigned short* __restrict__ wb,
                       int Cin, int Cout){
  int idx = blockIdx.x * TPB + threadIdx.x;
  int tot = 27 * Cout * Cin; if (idx >= tot) return;
  int ci = idx % Cin; int t = idx / Cin; int co = t % Cout; int tap = t / Cout;
  wb[idx] = f2b(w[((long)co * Cin + ci) * 27 + tap]);
}
// DHWIO fp32 -> [tap][COP][CIP] zero-padded (decoder tconvs)
__global__ void rp_dec(const float* __restrict__ w, unsigned short* __restrict__ wb,
                       int Cin, int Cout, int CIP, int COP){
  int idx = blockIdx.x * TPB + threadIdx.x;
  int tot = 27 * COP * CIP; if (idx >= tot) return;
  int ci = idx % CIP; int t = idx / CIP; int co = t % COP; int tap = t / COP;
  float v = (ci < Cin && co < Cout) ? w[((long)tap * Cin + ci) * Cout + co] : 0.f;
  wb[idx] = f2b(v);
}
// conv0 tap-paired: [pp<14][co<32][k<32], k<16 -> tap 2pp ci=k; k>=16 -> tap 2pp+1
__global__ void rp_pair(const float* __restrict__ w, unsigned short* __restrict__ wb){
  int idx = blockIdx.x * TPB + threadIdx.x;
  int tot = 14 * 32 * 32; if (idx >= tot) return;
  int k = idx & 31; int t = idx >> 5; int co = t & 31; int pp = t >> 5;
  int tap = pp * 2 + (k >> 4); int ci = k & 15;
  float v = (tap < 27) ? w[((long)co * 16 + ci) * 27 + tap] : 0.f;
  wb[idx] = f2b(v);
}

// ---------------- x transpose: NCDHW fp32 -> NDHWC bf16 (C=16) ----------------
__global__ void xpose_k(const float* __restrict__ x, unsigned short* __restrict__ xt){
  __shared__ float l[16][257];
  int t = threadIdx.x;
  long p0 = (long)blockIdx.x * 256;
  int n = (int)(p0 >> 18);                  // 262144 pts per n
  long off = p0 & 262143;
  const float* xb = x + ((long)n * 16) * 262144 + off;
#pragma unroll
  for (int c = 0; c < 16; ++c) l[c][t] = xb[(long)c * 262144 + t];
  __syncthreads();
  ushort8 u0, u1;
#pragma unroll
  for (int k = 0; k < 8; ++k){ u0[k] = f2b(l[k][t]); u1[k] = f2b(l[k + 8][t]); }
  unsigned short* o = xt + (p0 + t) * 16;
  *(ushort8*)o = u0; *(ushort8*)(o + 8) = u1;
}

// ---------------- unified NDHWC MFMA conv ----------------
// VARIANT 0: stride-1 conv pad1 (work grid = out grid = in grid G)
// VARIANT 1: stride-2 tconv octant (work grid = in half-grid G, out = 2G)
// VARIANT 2: stride-2 conv pad1 (work grid = out grid G, in grid 2G)
// Block: 4(d)x4(h)x16(w) tile; 4 waves, wave wv owns d-slice wv.
// Wave computes CO_TILES x 16co for 4 h-rows (j) of 16 w points.
template <int VARIANT, int CO_TILES, bool PAIRED, bool FOUT>
__global__ __launch_bounds__(TPB) void mconv(
    const unsigned short* __restrict__ inA, int CA,
    const unsigned short* __restrict__ inB, int CB,
    const unsigned short* __restrict__ wb,
    void* __restrict__ outv,
    int N, int Cout, int COP, int CIP, int G) {
  const int tid = threadIdx.x, wv = tid >> 6, l = tid & 63, l15 = l & 15, lg = l >> 4;
  int ntW = G >> 4, ntH = G >> 2, ntD = G >> 2;
  int bx = blockIdx.x;
  int w0 = (bx % ntW) << 4; bx /= ntW;
  int h0 = (bx % ntH) << 2; bx /= ntH;
  int d0 = (bx % ntD) << 2; int n = bx / ntD;
  const int co0 = blockIdx.y * (16 * CO_TILES);
  const int Gin = (VARIANT == 2) ? 2 * G : G;
  const long spin = (long)Gin * Gin * Gin;

  int pd = 0, ph = 0, pw = 0;
  int nkd, kd_[3], dd_[3], nkh, kh_[3], dh_[3], nkw, kw_[3], dw_[3];
  if constexpr (VARIANT == 1) {
    int oct = blockIdx.z;
    pd = (oct >> 2) & 1; ph = (oct >> 1) & 1; pw = oct & 1;
    if (pd){ nkd=1; kd_[0]=1; dd_[0]=0; } else { nkd=2; kd_[0]=0; dd_[0]=-1; kd_[1]=2; dd_[1]=0; }
    if (ph){ nkh=1; kh_[0]=1; dh_[0]=0; } else { nkh=2; kh_[0]=0; dh_[0]=-1; kh_[1]=2; dh_[1]=0; }
    if (pw){ nkw=1; kw_[0]=1; dw_[0]=0; } else { nkw=2; kw_[0]=0; dw_[0]=-1; kw_[1]=2; dw_[1]=0; }
  } else {
    nkd = nkh = nkw = 3;
#pragma unroll
    for (int i = 0; i < 3; ++i){ kd_[i]=i; dd_[i]=i-1; kh_[i]=i; dh_[i]=i-1; kw_[i]=i; dw_[i]=i-1; }
  }

  f32x4 acc[CO_TILES][4];
#pragma unroll
  for (int ct = 0; ct < CO_TILES; ++ct)
#pragma unroll
    for (int j = 0; j < 4; ++j) acc[ct][j] = (f32x4){0.f, 0.f, 0.f, 0.f};

  if constexpr (PAIRED) {
    // conv0: Cin=16, wb [pp][32co][32k]; per-lane tap select (lg half).
    const unsigned short* src = inA + (long)n * 16 * spin;
#pragma unroll 1
    for (int pp = 0; pp < 14; ++pp) {
      short8 A0 = *(const short8*)(wb + ((pp * 32 + l15) * 32) + lg * 8);
      short8 A1 = *(const short8*)(wb + ((pp * 32 + 16 + l15) * 32) + lg * 8);
      int t0 = 2 * pp + (lg >> 1); if (t0 > 26) t0 = 26;
      int dd = t0 / 9 - 1, dh = (t0 / 3) % 3 - 1, dw = t0 % 3 - 1;
      int gd = d0 + wv + dd, gw = w0 + l15 + dw;
      bool vdw = ((unsigned)gd < (unsigned)G) && ((unsigned)gw < (unsigned)G);
      int cio = (lg & 1) * 8;
#pragma unroll
      for (int j = 0; j < 4; ++j) {
        int gh = h0 + j + dh;
        short8 B = (short8){0,0,0,0,0,0,0,0};
        if (vdw && (unsigned)gh < (unsigned)G)
          B = *(const short8*)(src + (((long)gd * G + gh) * G + gw) * 16 + cio);
        acc[0][j] = __builtin_amdgcn_mfma_f32_16x16x32_bf16(A0, B, acc[0][j], 0, 0, 0);
        if (CO_TILES == 2)
          acc[1][j] = __builtin_amdgcn_mfma_f32_16x16x32_bf16(A1, B, acc[1][j], 0, 0, 0);
      }
    }
  } else {
    const int nch = CIP >> 5;
#pragma unroll 1
    for (int ch = 0; ch < nch; ++ch) {
      int c0 = ch << 5;
      const unsigned short* src; int Cs, cl_;
      if (c0 < CA){ src = inA; Cs = CA; cl_ = c0; } else { src = inB; Cs = CB; cl_ = c0 - CA; }
      const unsigned short* sb = src + (long)n * Cs * spin;
#pragma unroll 1
      for (int a = 0; a < nkd; ++a) {
        int gd = (VARIANT == 2) ? 2 * (d0 + wv) + kd_[a] - 1 : d0 + wv + dd_[a];
        bool vd = (unsigned)gd < (unsigned)Gin;
#pragma unroll 1
        for (int b = 0; b < nkh; ++b) {
#pragma unroll
          for (int c = 0; c < 3; ++c) {
            if (c >= nkw) break;
            int tap = (kd_[a] * 3 + kh_[b]) * 3 + kw_[c];
            const unsigned short* ap = wb + ((long)tap * COP + co0 + l15) * CIP + c0 + lg * 8;
            short8 A0 = *(const short8*)ap;
            short8 A1;
            if (CO_TILES == 2) A1 = *(const short8*)(ap + 16 * CIP);
            int gw = (VARIANT == 2) ? 2 * (w0 + l15) + kw_[c] - 1 : w0 + l15 + dw_[c];
            bool vdw = vd && ((unsigned)gw < (unsigned)Gin);
#pragma unroll
            for (int j = 0; j < 4; ++j) {
              int gh = (VARIANT == 2) ? 2 * (h0 + j) + kh_[b] - 1 : h0 + j + dh_[b];
              short8 B = (short8){0,0,0,0,0,0,0,0};
              if (vdw && (unsigned)gh < (unsigned)Gin)
                B = *(const short8*)(sb + (((long)gd * Gin + gh) * Gin + gw) * Cs + cl_ + lg * 8);
              acc[0][j] = __builtin_amdgcn_mfma_f32_16x16x32_bf16(A0, B, acc[0][j], 0, 0, 0);
              if (CO_TILES == 2)
                acc[1][j] = __builtin_amdgcn_mfma_f32_16x16x32_bf16(A1, B, acc[1][j], 0, 0, 0);
            }
          }
        }
      }
    }
  }

  // ---- store ----
  const int Go = (VARIANT == 1) ? 2 * G : G;
  const long spo = (long)Go * Go * Go;
  int od = (VARIANT == 1) ? 2 * (d0 + wv) + pd : d0 + wv;
#pragma unroll
  for (int j = 0; j < 4; ++j) {
    int oh = (VARIANT == 1) ? 2 * (h0 + j) + ph : h0 + j;
    int ow = (VARIANT == 1) ? 2 * (w0 + l15) + pw : w0 + l15;
    long pt = ((long)od * Go + oh) * Go + ow;
    if constexpr (!FOUT) {
      unsigned short* outp = (unsigned short*)outv;
#pragma unroll
      for (int ct = 0; ct < CO_TILES; ++ct) {
        ushort4v pk;
#pragma unroll
        for (int r = 0; r < 4; ++r) pk[r] = f2b(acc[ct][j][r]);
        *(ushort4v*)(outp + ((long)n * spo + pt) * Cout + co0 + ct * 16 + lg * 4) = pk;
      }
    } else {
      float* outp = (float*)outv;
#pragma unroll
      for (int ct = 0; ct < CO_TILES; ++ct)
#pragma unroll
        for (int r = 0; r < 4; ++r) {
          int co = co0 + ct * 16 + lg * 4 + r;
          if (co < Cout) outp[((long)(n * Cout + co)) * spo + pt] = acc[ct][j][r];
        }
    }
  }
}

// ---------------- BN stats stage 1 (channels-last) ----------------
__global__ void bn_stats1_cl(const unsigned short* __restrict__ x, float* __restrict__ part,
                             long npts, int C, int lC, int K){
  int chunk = blockIdx.x, tid = threadIdx.x;
  int c = tid & (C - 1); int pr = tid >> lC; int PR = TPB >> lC;
  float s = 0.f, q = 0.f;
  for (long p = (long)chunk * PR + pr; p < npts; p += (long)K * PR) {
    float f = b2f(x[p * C + c]); s += f; q += f * f;
  }
  __shared__ float shs[TPB], shq[TPB];
  shs[tid] = s; shq[tid] = q;
  __syncthreads();
  for (int off = TPB / 2; off >= C; off >>= 1) {
    if (tid < off) { shs[tid] += shs[tid + off]; shq[tid] += shq[tid + off]; }
    __syncthreads();
  }
  if (tid < C) { part[((long)tid * K + chunk) * 2] = shs[tid]; part[((long)tid * K + chunk) * 2 + 1] = shq[tid]; }
}

// ---------------- BN stats stage 2 ----------------
__global__ void bn_stats2_k(const float* __restrict__ part, const float* __restrict__ g,
                            const float* __restrict__ b, float* __restrict__ scale,
                            float* __restrict__ shift, int C, int K, float inv_cnt) {
  int c = blockIdx.x * blockDim.x + threadIdx.x;
  if (c >= C) return;
  float s = 0.f, q = 0.f;
  for (int k = 0; k < K; ++k) { s += part[((long)c * K + k) * 2]; q += part[((long)c * K + k) * 2 + 1]; }
  float m = s * inv_cnt, v = q * inv_cnt - m * m;
  float rs = rsqrtf(v + 1e-5f) * g[c];
  scale[c] = rs;
  shift[c] = b[c] - m * rs;
}

// ---------------- BN apply + ReLU (channels-last, vectorized) ----------------
__global__ void bn_relu_cl(unsigned short* __restrict__ x, const float* __restrict__ sc,
                           const float* __restrict__ sh, int C, long tot8){
  long i8 = (long)blockIdx.x * TPB + threadIdx.x;
  if (i8 >= tot8) return;
  long e = i8 * 8;
  int c0 = (int)(e & (C - 1));
  float4v s0 = *(const float4v*)(sc + c0), s1 = *(const float4v*)(sc + c0 + 4);
  float4v h0 = *(const float4v*)(sh + c0), h1 = *(const float4v*)(sh + c0 + 4);
  ushort8 v = *(ushort8*)(x + e);
  ushort8 r;
#pragma unroll
  for (int j = 0; j < 4; ++j) {
    float y = b2f(v[j]) * s0[j] + h0[j];
    r[j] = f2b(y > 0.f ? y : 0.f);
  }
#pragma unroll
  for (int j = 0; j < 4; ++j) {
    float y = b2f(v[j + 4]) * s1[j] + h1[j];
    r[j + 4] = f2b(y > 0.f ? y : 0.f);
  }
  *(ushort8*)(x + e) = r;
}

extern "C" void kernel_launch(void* const* d_in, const int* in_sizes, int n_in,
                              void* d_out, int out_size, void* d_ws, size_t ws_size,
                              hipStream_t stream) {
  const float* x    = (const float*)d_in[0];
  const float* w0   = (const float*)d_in[1];
  const float* g0   = (const float*)d_in[2];
  const float* b0   = (const float*)d_in[3];
  const float* w1   = (const float*)d_in[4];
  const float* g1   = (const float*)d_in[5];
  const float* b1   = (const float*)d_in[6];
  const float* w2   = (const float*)d_in[7];
  const float* g2   = (const float*)d_in[8];
  const float* b2   = (const float*)d_in[9];
  const float* wt2r = (const float*)d_in[10];
  const float* g2r  = (const float*)d_in[11];
  const float* b2r  = (const float*)d_in[12];
  const float* wt1r = (const float*)d_in[13];
  const float* g1r  = (const float*)d_in[14];
  const float* b1r  = (const float*)d_in[15];
  const float* wt0r = (const float*)d_in[16];
  const float* wt2c = (const float*)d_in[17];
  const float* g2c  = (const float*)d_in[18];
  const float* b2c  = (const float*)d_in[19];
  const float* wt1c = (const float*)d_in[20];
  const float* g1c  = (const float*)d_in[21];
  const float* b1c  = (const float*)d_in[22];
  const float* wt0c = (const float*)d_in[23];

  const int N = 2;
  const long sp64 = 262144, sp32 = 32768, sp16 = 4096;
  const int K = 256;  // bn chunks

  // ---- workspace (ushort units), all activations NDHWC bf16 ----
  unsigned short* W = (unsigned short*)d_ws;
  unsigned short* s1   = W;                       // [2*sp64][32]  16,777,216
  unsigned short* s2   = s1  + 16777216;          // [2*sp32][64]   4,194,304
  unsigned short* s4   = s2  + 4194304;           // [2*sp16][128]  1,048,576
  unsigned short* r32  = s4  + 1048576;           // [2*sp32][64]   4,194,304
  unsigned short* c32  = r32 + 4194304;           // [2*sp32][64]   4,194,304
  unsigned short* r64  = c32 + 4194304;           // [2*sp64][32]  16,777,216
  unsigned short* xt   = r64;                     // alias: [2*sp64][16] (dead after conv0)
  unsigned short* c64  = r64 + 16777216;          // [2*sp64][64]  33,554,432
  unsigned short* wb0p = c64 + 33554432;          // 14*32*32 = 14,336
  unsigned short* wb1  = wb0p + 14336;            // 27*64*32 = 55,296
  unsigned short* wb2  = wb1  + 55296;            // 27*128*64 = 221,184
  unsigned short* wb2r = wb2  + 221184;           // 27*64*128
  unsigned short* wb2c = wb2r + 221184;
  unsigned short* wb1r = wb2c + 221184;           // 27*32*64 = 55,296
  unsigned short* wb1c = wb1r + 55296;            // 27*64*128
  unsigned short* wbrec= wb1c + 221184;           // 27*16*32 = 13,824
  unsigned short* wbcl = wbrec+ 13824;            // 27*16*96 = 41,472
  float* part = (float*)(wbcl + 41472);           // 128*K*2 = 65,536 f32
  float* bsc  = part + 128L * K * 2;
  float* bsh  = bsc + 128;

  float* out_cl  = (float*)d_out;                 // [2][2][64^3] NCDHW
  float* out_rec = (float*)d_out + 2L * 2 * sp64; // [2][16][64^3]

  // ---- weight repacks ----
  rp_pair<<<cdiv_l(14L*32*32, TPB), TPB, 0, stream>>>(w0, wb0p);
  rp_enc<<<cdiv_l(27L*64*32, TPB), TPB, 0, stream>>>(w1, wb1, 32, 64);
  rp_enc<<<cdiv_l(27L*128*64, TPB), TPB, 0, stream>>>(w2, wb2, 64, 128);
  rp_dec<<<cdiv_l(27L*64*128, TPB), TPB, 0, stream>>>(wt2r, wb2r, 128, 64, 128, 64);
  rp_dec<<<cdiv_l(27L*64*128, TPB), TPB, 0, stream>>>(wt2c, wb2c, 128, 64, 128, 64);
  rp_dec<<<cdiv_l(27L*32*64, TPB), TPB, 0, stream>>>(wt1r, wb1r, 64, 32, 64, 32);
  rp_dec<<<cdiv_l(27L*64*128, TPB), TPB, 0, stream>>>(wt1c, wb1c, 128, 64, 128, 64);
  rp_dec<<<cdiv_l(27L*16*32, TPB), TPB, 0, stream>>>(wt0r, wbrec, 32, 16, 32, 16);
  rp_dec<<<cdiv_l(27L*16*96, TPB), TPB, 0, stream>>>(wt0c, wbcl, 96, 2, 96, 16);

  // ---- x -> NDHWC bf16 ----
  xpose_k<<<2048, TPB, 0, stream>>>(x, xt);

  auto bn = [&](unsigned short* t, const float* g, const float* b, int C, int lC, long npts) {
    bn_stats1_cl<<<K, TPB, 0, stream>>>(t, part, npts, C, lC, K);
    bn_stats2_k<<<1, 128, 0, stream>>>(part, g, b, bsc, bsh, C, K, 1.f / (float)(npts));
    long tot8 = npts * C / 8;
    bn_relu_cl<<<cdiv_l(tot8, TPB), TPB, 0, stream>>>(t, bsc, bsh, C, tot8);
  };

  // grid helper: blocks = N * (G/4 d) * (G/4 h) * (G/16 w)
  auto gx = [&](int G){ return (unsigned)(N * (G >> 2) * (G >> 2) * (G >> 4)); };

  // ---- encoder ----
  // conv0: 16->32, 64^3, stride1, paired taps
  mconv<0, 2, true, false><<<dim3(gx(64), 1), TPB, 0, stream>>>(
      xt, 16, nullptr, 0, wb0p, s1, N, 32, 32, 32, 64);
  bn(s1, g0, b0, 32, 5, 2 * sp64);
  // conv1: 32->64, stride2, out 32^3
  mconv<2, 2, false, false><<<dim3(gx(32), 2), TPB, 0, stream>>>(
      s1, 32, nullptr, 0, wb1, s2, N, 64, 64, 32, 32);
  bn(s2, g1, b1, 64, 6, 2 * sp32);
  // conv2: 64->128, stride2, out 16^3
  mconv<2, 2, false, false><<<dim3(gx(16), 4), TPB, 0, stream>>>(
      s2, 64, nullptr, 0, wb2, s4, N, 128, 128, 64, 16);
  bn(s4, g2, b2, 128, 7, 2 * sp16);

  // ---- level-2 tconvs (16 -> 32), octants ----
  mconv<1, 2, false, false><<<dim3(gx(16), 2, 8), TPB, 0, stream>>>(
      s4, 128, nullptr, 0, wb2r, r32, N, 64, 64, 128, 16);
  bn(r32, g2r, b2r, 64, 6, 2 * sp32);
  mconv<1, 2, false, false><<<dim3(gx(16), 2, 8), TPB, 0, stream>>>(
      s4, 128, nullptr, 0, wb2c, c32, N, 64, 64, 128, 16);
  bn(c32, g2c, b2c, 64, 6, 2 * sp32);

  // ---- level-1 tconvs (32 -> 64), octants ----
  mconv<1, 2, false, false><<<dim3(gx(32), 1, 8), TPB, 0, stream>>>(
      r32, 64, nullptr, 0, wb1r, r64, N, 32, 32, 64, 32);
  bn(r64, g1r, b1r, 32, 5, 2 * sp64);
  mconv<1, 2, false, false><<<dim3(gx(32), 2, 8), TPB, 0, stream>>>(
      c32, 64, s2, 64, wb1c, c64, N, 64, 64, 128, 32);
  bn(c64, g1c, b1c, 64, 6, 2 * sp64);

  // ---- level-0 tconvs (stride1, no BN) -> fp32 NCDHW outputs ----
  mconv<0, 1, false, true><<<dim3(gx(64), 1), TPB, 0, stream>>>(
      r64, 32, nullptr, 0, wbrec, out_rec, N, 16, 16, 32, 64);
  mconv<0, 1, false, true><<<dim3(gx(64), 1), TPB, 0, stream>>>(
      c64, 64, s1, 32, wbcl, out_cl, N, 2, 16, 96, 64);
}

// Round 7
// 1208.271 us; speedup vs baseline: 3.2135x; 1.4008x over previous
//
#include <hip/hip_runtime.h>
#include <hip/hip_bf16.h>

// ---------------------------------------------------------------------------
// UNet3D dense forward, round 7: NDHWC implicit-GEMM MFMA.
//  - stride-1 convs (conv0 / rec0 / cl0): LDS-staged B operands. SoA layout
//    xs[ciOctet][pt(pad 652)][8] -> 16B-aligned ds_read_b128 at 16B lane
//    stride (conflict-free); halo zeros staged so inner loop is branch-free.
//  - stride-2 conv + octant tconv: direct global B (L2-resident inputs).
//  - weights bf16 [tap][co][ci]; A-frags 16B global loads (hot in L1/L2).
// ---------------------------------------------------------------------------

using bf16 = __hip_bfloat16;
using ushort4v = __attribute__((ext_vector_type(4))) unsigned short;
using ushort8  = __attribute__((ext_vector_type(8))) unsigned short;
using short8   = __attribute__((ext_vector_type(8))) short;
using f32x4    = __attribute__((ext_vector_type(4))) float;
using float4v  = __attribute__((ext_vector_type(4))) float;

#define TPB 256

static inline int cdiv_l(long a, int b){ return (int)((a + b - 1) / b); }

__device__ __forceinline__ float b2f(unsigned short u){
  union { unsigned int i; float f; } v; v.i = ((unsigned int)u) << 16; return v.f;
}
__device__ __forceinline__ unsigned short f2b(float f){
  union { bf16 h; unsigned short u; } v; v.h = __float2bfloat16(f); return v.u;
}

// ---------------- weight repacks (bf16) ----------------
__global__ void rp_enc(const float* __restrict__ w, unsigned short* __restrict__ wb,
                       int Cin, int Cout){
  int idx = blockIdx.x * TPB + threadIdx.x;
  int tot = 27 * Cout * Cin; if (idx >= tot) return;
  int ci = idx % Cin; int t = idx / Cin; int co = t % Cout; int tap = t / Cout;
  wb[idx] = f2b(w[((long)co * Cin + ci) * 27 + tap]);
}
__global__ void rp_dec(const float* __restrict__ w, unsigned short* __restrict__ wb,
                       int Cin, int Cout, int CIP, int COP){
  int idx = blockIdx.x * TPB + threadIdx.x;
  int tot = 27 * COP * CIP; if (idx >= tot) return;
  int ci = idx % CIP; int t = idx / CIP; int co = t % COP; int tap = t / COP;
  float v = (ci < Cin && co < Cout) ? w[((long)tap * Cin + ci) * Cout + co] : 0.f;
  wb[idx] = f2b(v);
}
// conv0 tap-paired: [pp<14][co<32][k<32], k<16 -> tap 2pp ci=k; k>=16 -> tap 2pp+1
__global__ void rp_pair(const float* __restrict__ w, unsigned short* __restrict__ wb){
  int idx = blockIdx.x * TPB + threadIdx.x;
  int tot = 14 * 32 * 32; if (idx >= tot) return;
  int k = idx & 31; int t = idx >> 5; int co = t & 31; int pp = t >> 5;
  int tap = pp * 2 + (k >> 4); int ci = k & 15;
  float v = (tap < 27) ? w[((long)co * 16 + ci) * 27 + tap] : 0.f;
  wb[idx] = f2b(v);
}

// ---------------- x transpose: NCDHW fp32 -> NDHWC bf16 (C=16) ----------------
__global__ void xpose_k(const float* __restrict__ x, unsigned short* __restrict__ xt){
  __shared__ float l[16][257];
  int t = threadIdx.x;
  long p0 = (long)blockIdx.x * 256;
  int n = (int)(p0 >> 18);
  long off = p0 & 262143;
  const float* xb = x + ((long)n * 16) * 262144 + off;
#pragma unroll
  for (int c = 0; c < 16; ++c) l[c][t] = xb[(long)c * 262144 + t];
  __syncthreads();
  ushort8 u0, u1;
#pragma unroll
  for (int k = 0; k < 8; ++k){ u0[k] = f2b(l[k][t]); u1[k] = f2b(l[k + 8][t]); }
  unsigned short* o = xt + (p0 + t) * 16;
  *(ushort8*)o = u0; *(ushort8*)(o + 8) = u1;
}

// ---------------- unified NDHWC MFMA conv ----------------
// VARIANT 0: stride-1 conv pad1, LDS-staged B.
// VARIANT 1: stride-2 tconv octant (grid.z), direct-global B.
// VARIANT 2: stride-2 conv pad1, direct-global B.
// Block: 4(d)x4(h)x16(w) tile; 4 waves, wave wv owns d-slice wv.
template <int VARIANT, int CO_TILES, bool PAIRED, bool FOUT>
__global__ __launch_bounds__(TPB) void mconv(
    const unsigned short* __restrict__ inA, int CA,
    const unsigned short* __restrict__ inB, int CB,
    const unsigned short* __restrict__ wb,
    void* __restrict__ outv,
    int N, int Cout, int COP, int CIP, int G) {
  const int tid = threadIdx.x, wv = tid >> 6, l = tid & 63, l15 = l & 15, lg = l >> 4;
  int ntW = G >> 4, ntH = G >> 2, ntD = G >> 2;
  int bx = blockIdx.x;
  int w0 = (bx % ntW) << 4; bx /= ntW;
  int h0 = (bx % ntH) << 2; bx /= ntH;
  int d0 = (bx % ntD) << 2; int n = bx / ntD;
  const int co0 = blockIdx.y * (16 * CO_TILES);
  const int Gin = (VARIANT == 2) ? 2 * G : G;
  const long spin = (long)Gin * Gin * Gin;

  f32x4 acc[CO_TILES][4];
#pragma unroll
  for (int ct = 0; ct < CO_TILES; ++ct)
#pragma unroll
    for (int j = 0; j < 4; ++j) acc[ct][j] = (f32x4){0.f, 0.f, 0.f, 0.f};

  int pd = 0, ph = 0, pw = 0;

  if constexpr (PAIRED) {
    // conv0: Cin=16 (2 ci-octets), K packs 2 taps. LDS-staged.
    __shared__ unsigned short xs[2 * 652 * 8];
    const unsigned short* src = inA + (long)n * 16 * spin;
    for (int idx = tid; idx < 2 * 648; idx += TPB) {
      int q = idx / 648, pt = idx - q * 648;
      int zw = pt % 18; int zt = pt / 18; int zh = zt % 6; int zd = zt / 6;
      int gd = d0 + zd - 1, gh = h0 + zh - 1, gw = w0 + zw - 1;
      ushort8 v = (ushort8){0,0,0,0,0,0,0,0};
      if ((unsigned)gd < (unsigned)G && (unsigned)gh < (unsigned)G && (unsigned)gw < (unsigned)G)
        v = *(const ushort8*)(src + (((long)gd * G + gh) * G + gw) * 16 + q * 8);
      *(ushort8*)(xs + (q * 652 + pt) * 8) = v;
    }
    __syncthreads();
#pragma unroll 1
    for (int pp = 0; pp < 14; ++pp) {
      short8 A0 = *(const short8*)(wb + ((pp * 32 + l15) * 32) + lg * 8);
      short8 A1 = *(const short8*)(wb + ((pp * 32 + 16 + l15) * 32) + lg * 8);
      int t0 = 2 * pp + (lg >> 1); if (t0 > 26) t0 = 26;
      int dd = t0 / 9 - 1, dh = (t0 / 3) % 3 - 1, dw = t0 % 3 - 1;
      int q = lg & 1;
      int zd = wv + 1 + dd;
      int base = (q * 652 + zd * 108 + (1 + dh) * 18 + 1 + l15 + dw) * 8;
#pragma unroll
      for (int j = 0; j < 4; ++j) {
        short8 B = *(const short8*)(xs + base + j * (18 * 8));
        acc[0][j] = __builtin_amdgcn_mfma_f32_16x16x32_bf16(A0, B, acc[0][j], 0, 0, 0);
        if (CO_TILES == 2)
          acc[1][j] = __builtin_amdgcn_mfma_f32_16x16x32_bf16(A1, B, acc[1][j], 0, 0, 0);
      }
    }
  } else if constexpr (VARIANT == 0) {
    // stride-1 conv, LDS-staged per 32-ci chunk.
    __shared__ unsigned short xs[4 * 652 * 8];
    const int nch = CIP >> 5;
#pragma unroll 1
    for (int ch = 0; ch < nch; ++ch) {
      int c0 = ch << 5;
      const unsigned short* src; int Cs, cl_;
      if (c0 < CA){ src = inA; Cs = CA; cl_ = c0; } else { src = inB; Cs = CB; cl_ = c0 - CA; }
      const unsigned short* sb = src + (long)n * Cs * spin;
      __syncthreads();
      for (int idx = tid; idx < 4 * 648; idx += TPB) {
        int q = idx / 648, pt = idx - q * 648;
        int zw = pt % 18; int zt = pt / 18; int zh = zt % 6; int zd = zt / 6;
        int gd = d0 + zd - 1, gh = h0 + zh - 1, gw = w0 + zw - 1;
        ushort8 v = (ushort8){0,0,0,0,0,0,0,0};
        if ((unsigned)gd < (unsigned)G && (unsigned)gh < (unsigned)G && (unsigned)gw < (unsigned)G)
          v = *(const ushort8*)(sb + (((long)gd * G + gh) * G + gw) * Cs + cl_ + q * 8);
        *(ushort8*)(xs + (q * 652 + pt) * 8) = v;
      }
      __syncthreads();
#pragma unroll 1
      for (int a = 0; a < 3; ++a) {
        int zd = wv + a;
#pragma unroll 1
        for (int b = 0; b < 3; ++b) {
#pragma unroll
          for (int c = 0; c < 3; ++c) {
            int tap = (a * 3 + b) * 3 + c;
            const unsigned short* ap = wb + ((long)tap * COP + co0 + l15) * CIP + c0 + lg * 8;
            short8 A0 = *(const short8*)ap;
            short8 A1;
            if (CO_TILES == 2) A1 = *(const short8*)(ap + 16 * CIP);
            int base = (lg * 652 + zd * 108 + b * 18 + l15 + c) * 8;
#pragma unroll
            for (int j = 0; j < 4; ++j) {
              short8 B = *(const short8*)(xs + base + j * (18 * 8));
              acc[0][j] = __builtin_amdgcn_mfma_f32_16x16x32_bf16(A0, B, acc[0][j], 0, 0, 0);
              if (CO_TILES == 2)
                acc[1][j] = __builtin_amdgcn_mfma_f32_16x16x32_bf16(A1, B, acc[1][j], 0, 0, 0);
            }
          }
        }
      }
    }
  } else {
    // direct-global B (V1 octant tconv / V2 stride-2 conv)
    int nkd, kd_[3], dd_[3], nkh, kh_[3], dh_[3], nkw, kw_[3], dw_[3];
    if constexpr (VARIANT == 1) {
      int oct = blockIdx.z;
      pd = (oct >> 2) & 1; ph = (oct >> 1) & 1; pw = oct & 1;
      if (pd){ nkd=1; kd_[0]=1; dd_[0]=0; } else { nkd=2; kd_[0]=0; dd_[0]=-1; kd_[1]=2; dd_[1]=0; }
      if (ph){ nkh=1; kh_[0]=1; dh_[0]=0; } else { nkh=2; kh_[0]=0; dh_[0]=-1; kh_[1]=2; dh_[1]=0; }
      if (pw){ nkw=1; kw_[0]=1; dw_[0]=0; } else { nkw=2; kw_[0]=0; dw_[0]=-1; kw_[1]=2; dw_[1]=0; }
    } else {
      nkd = nkh = nkw = 3;
#pragma unroll
      for (int i = 0; i < 3; ++i){ kd_[i]=i; dd_[i]=i-1; kh_[i]=i; dh_[i]=i-1; kw_[i]=i; dw_[i]=i-1; }
    }
    const int nch = CIP >> 5;
#pragma unroll 1
    for (int ch = 0; ch < nch; ++ch) {
      int c0 = ch << 5;
      const unsigned short* src; int Cs, cl_;
      if (c0 < CA){ src = inA; Cs = CA; cl_ = c0; } else { src = inB; Cs = CB; cl_ = c0 - CA; }
      const unsigned short* sb = src + (long)n * Cs * spin;
#pragma unroll 1
      for (int a = 0; a < nkd; ++a) {
        int gd = (VARIANT == 2) ? 2 * (d0 + wv) + kd_[a] - 1 : d0 + wv + dd_[a];
        bool vd = (unsigned)gd < (unsigned)Gin;
#pragma unroll 1
        for (int b = 0; b < nkh; ++b) {
#pragma unroll
          for (int c = 0; c < 3; ++c) {
            if (c >= nkw) break;
            int tap = (kd_[a] * 3 + kh_[b]) * 3 + kw_[c];
            const unsigned short* ap = wb + ((long)tap * COP + co0 + l15) * CIP + c0 + lg * 8;
            short8 A0 = *(const short8*)ap;
            short8 A1;
            if (CO_TILES == 2) A1 = *(const short8*)(ap + 16 * CIP);
            int gw = (VARIANT == 2) ? 2 * (w0 + l15) + kw_[c] - 1 : w0 + l15 + dw_[c];
            bool vdw = vd && ((unsigned)gw < (unsigned)Gin);
#pragma unroll
            for (int j = 0; j < 4; ++j) {
              int gh = (VARIANT == 2) ? 2 * (h0 + j) + kh_[b] - 1 : h0 + j + dh_[b];
              short8 B = (short8){0,0,0,0,0,0,0,0};
              if (vdw && (unsigned)gh < (unsigned)Gin)
                B = *(const short8*)(sb + (((long)gd * Gin + gh) * Gin + gw) * Cs + cl_ + lg * 8);
              acc[0][j] = __builtin_amdgcn_mfma_f32_16x16x32_bf16(A0, B, acc[0][j], 0, 0, 0);
              if (CO_TILES == 2)
                acc[1][j] = __builtin_amdgcn_mfma_f32_16x16x32_bf16(A1, B, acc[1][j], 0, 0, 0);
            }
          }
        }
      }
    }
  }

  // ---- store ----
  const int Go = (VARIANT == 1) ? 2 * G : G;
  const long spo = (long)Go * Go * Go;
  int od = (VARIANT == 1) ? 2 * (d0 + wv) + pd : d0 + wv;
#pragma unroll
  for (int j = 0; j < 4; ++j) {
    int oh = (VARIANT == 1) ? 2 * (h0 + j) + ph : h0 + j;
    int ow = (VARIANT == 1) ? 2 * (w0 + l15) + pw : w0 + l15;
    long pt = ((long)od * Go + oh) * Go + ow;
    if constexpr (!FOUT) {
      unsigned short* outp = (unsigned short*)outv;
#pragma unroll
      for (int ct = 0; ct < CO_TILES; ++ct) {
        ushort4v pk;
#pragma unroll
        for (int r = 0; r < 4; ++r) pk[r] = f2b(acc[ct][j][r]);
        *(ushort4v*)(outp + ((long)n * spo + pt) * Cout + co0 + ct * 16 + lg * 4) = pk;
      }
    } else {
      float* outp = (float*)outv;
#pragma unroll
      for (int ct = 0; ct < CO_TILES; ++ct)
#pragma unroll
        for (int r = 0; r < 4; ++r) {
          int co = co0 + ct * 16 + lg * 4 + r;
          if (co < Cout) outp[((long)(n * Cout + co)) * spo + pt] = acc[ct][j][r];
        }
    }
  }
}

// ---------------- BN stats stage 1 (channels-last) ----------------
__global__ void bn_stats1_cl(const unsigned short* __restrict__ x, float* __restrict__ part,
                             long npts, int C, int lC, int K){
  int chunk = blockIdx.x, tid = threadIdx.x;
  int c = tid & (C - 1); int pr = tid >> lC; int PR = TPB >> lC;
  float s = 0.f, q = 0.f;
  for (long p = (long)chunk * PR + pr; p < npts; p += (long)K * PR) {
    float f = b2f(x[p * C + c]); s += f; q += f * f;
  }
  __shared__ float shs[TPB], shq[TPB];
  shs[tid] = s; shq[tid] = q;
  __syncthreads();
  for (int off = TPB / 2; off >= C; off >>= 1) {
    if (tid < off) { shs[tid] += shs[tid + off]; shq[tid] += shq[tid + off]; }
    __syncthreads();
  }
  if (tid < C) { part[((long)tid * K + chunk) * 2] = shs[tid]; part[((long)tid * K + chunk) * 2 + 1] = shq[tid]; }
}

// ---------------- BN stats stage 2 ----------------
__global__ void bn_stats2_k(const float* __restrict__ part, const float* __restrict__ g,
                            const float* __restrict__ b, float* __restrict__ scale,
                            float* __restrict__ shift, int C, int K, float inv_cnt) {
  int c = blockIdx.x * blockDim.x + threadIdx.x;
  if (c >= C) return;
  float s = 0.f, q = 0.f;
  for (int k = 0; k < K; ++k) { s += part[((long)c * K + k) * 2]; q += part[((long)c * K + k) * 2 + 1]; }
  float m = s * inv_cnt, v = q * inv_cnt - m * m;
  float rs = rsqrtf(v + 1e-5f) * g[c];
  scale[c] = rs;
  shift[c] = b[c] - m * rs;
}

// ---------------- BN apply + ReLU (channels-last, vectorized) ----------------
__global__ void bn_relu_cl(unsigned short* __restrict__ x, const float* __restrict__ sc,
                           const float* __restrict__ sh, int C, long tot8){
  long i8 = (long)blockIdx.x * TPB + threadIdx.x;
  if (i8 >= tot8) return;
  long e = i8 * 8;
  int c0 = (int)(e & (C - 1));
  float4v s0 = *(const float4v*)(sc + c0), s1 = *(const float4v*)(sc + c0 + 4);
  float4v h0 = *(const float4v*)(sh + c0), h1 = *(const float4v*)(sh + c0 + 4);
  ushort8 v = *(ushort8*)(x + e);
  ushort8 r;
#pragma unroll
  for (int j = 0; j < 4; ++j) {
    float y = b2f(v[j]) * s0[j] + h0[j];
    r[j] = f2b(y > 0.f ? y : 0.f);
  }
#pragma unroll
  for (int j = 0; j < 4; ++j) {
    float y = b2f(v[j + 4]) * s1[j] + h1[j];
    r[j + 4] = f2b(y > 0.f ? y : 0.f);
  }
  *(ushort8*)(x + e) = r;
}

extern "C" void kernel_launch(void* const* d_in, const int* in_sizes, int n_in,
                              void* d_out, int out_size, void* d_ws, size_t ws_size,
                              hipStream_t stream) {
  const float* x    = (const float*)d_in[0];
  const float* w0   = (const float*)d_in[1];
  const float* g0   = (const float*)d_in[2];
  const float* b0   = (const float*)d_in[3];
  const float* w1   = (const float*)d_in[4];
  const float* g1   = (const float*)d_in[5];
  const float* b1   = (const float*)d_in[6];
  const float* w2   = (const float*)d_in[7];
  const float* g2   = (const float*)d_in[8];
  const float* b2   = (const float*)d_in[9];
  const float* wt2r = (const float*)d_in[10];
  const float* g2r  = (const float*)d_in[11];
  const float* b2r  = (const float*)d_in[12];
  const float* wt1r = (const float*)d_in[13];
  const float* g1r  = (const float*)d_in[14];
  const float* b1r  = (const float*)d_in[15];
  const float* wt0r = (const float*)d_in[16];
  const float* wt2c = (const float*)d_in[17];
  const float* g2c  = (const float*)d_in[18];
  const float* b2c  = (const float*)d_in[19];
  const float* wt1c = (const float*)d_in[20];
  const float* g1c  = (const float*)d_in[21];
  const float* b1c  = (const float*)d_in[22];
  const float* wt0c = (const float*)d_in[23];

  const int N = 2;
  const long sp64 = 262144, sp32 = 32768, sp16 = 4096;
  const int K = 256;  // bn chunks

  // ---- workspace (ushort units), all activations NDHWC bf16 ----
  unsigned short* W = (unsigned short*)d_ws;
  unsigned short* s1   = W;                       // [2*sp64][32]
  unsigned short* s2   = s1  + 16777216;          // [2*sp32][64]
  unsigned short* s4   = s2  + 4194304;           // [2*sp16][128]
  unsigned short* r32  = s4  + 1048576;           // [2*sp32][64]
  unsigned short* c32  = r32 + 4194304;           // [2*sp32][64]
  unsigned short* r64  = c32 + 4194304;           // [2*sp64][32]
  unsigned short* xt   = r64;                     // alias (dead after conv0)
  unsigned short* c64  = r64 + 16777216;          // [2*sp64][64]
  unsigned short* wb0p = c64 + 33554432;          // 14*32*32
  unsigned short* wb1  = wb0p + 14336;            // 27*64*32
  unsigned short* wb2  = wb1  + 55296;            // 27*128*64
  unsigned short* wb2r = wb2  + 221184;           // 27*64*128
  unsigned short* wb2c = wb2r + 221184;
  unsigned short* wb1r = wb2c + 221184;           // 27*32*64
  unsigned short* wb1c = wb1r + 55296;            // 27*64*128
  unsigned short* wbrec= wb1c + 221184;           // 27*16*32
  unsigned short* wbcl = wbrec+ 13824;            // 27*16*96
  float* part = (float*)(wbcl + 41472);
  float* bsc  = part + 128L * K * 2;
  float* bsh  = bsc + 128;

  float* out_cl  = (float*)d_out;                 // [2][2][64^3] NCDHW
  float* out_rec = (float*)d_out + 2L * 2 * sp64; // [2][16][64^3]

  // ---- weight repacks ----
  rp_pair<<<cdiv_l(14L*32*32, TPB), TPB, 0, stream>>>(w0, wb0p);
  rp_enc<<<cdiv_l(27L*64*32, TPB), TPB, 0, stream>>>(w1, wb1, 32, 64);
  rp_enc<<<cdiv_l(27L*128*64, TPB), TPB, 0, stream>>>(w2, wb2, 64, 128);
  rp_dec<<<cdiv_l(27L*64*128, TPB), TPB, 0, stream>>>(wt2r, wb2r, 128, 64, 128, 64);
  rp_dec<<<cdiv_l(27L*64*128, TPB), TPB, 0, stream>>>(wt2c, wb2c, 128, 64, 128, 64);
  rp_dec<<<cdiv_l(27L*32*64, TPB), TPB, 0, stream>>>(wt1r, wb1r, 64, 32, 64, 32);
  rp_dec<<<cdiv_l(27L*64*128, TPB), TPB, 0, stream>>>(wt1c, wb1c, 128, 64, 128, 64);
  rp_dec<<<cdiv_l(27L*16*32, TPB), TPB, 0, stream>>>(wt0r, wbrec, 32, 16, 32, 16);
  rp_dec<<<cdiv_l(27L*16*96, TPB), TPB, 0, stream>>>(wt0c, wbcl, 96, 2, 96, 16);

  // ---- x -> NDHWC bf16 ----
  xpose_k<<<2048, TPB, 0, stream>>>(x, xt);

  auto bn = [&](unsigned short* t, const float* g, const float* b, int C, int lC, long npts) {
    bn_stats1_cl<<<K, TPB, 0, stream>>>(t, part, npts, C, lC, K);
    bn_stats2_k<<<1, 128, 0, stream>>>(part, g, b, bsc, bsh, C, K, 1.f / (float)(npts));
    long tot8 = npts * C / 8;
    bn_relu_cl<<<cdiv_l(tot8, TPB), TPB, 0, stream>>>(t, bsc, bsh, C, tot8);
  };

  auto gx = [&](int G){ return (unsigned)(N * (G >> 2) * (G >> 2) * (G >> 4)); };

  // ---- encoder ----
  mconv<0, 2, true, false><<<dim3(gx(64), 1), TPB, 0, stream>>>(
      xt, 16, nullptr, 0, wb0p, s1, N, 32, 32, 32, 64);
  bn(s1, g0, b0, 32, 5, 2 * sp64);
  mconv<2, 2, false, false><<<dim3(gx(32), 2), TPB, 0, stream>>>(
      s1, 32, nullptr, 0, wb1, s2, N, 64, 64, 32, 32);
  bn(s2, g1, b1, 64, 6, 2 * sp32);
  mconv<2, 2, false, false><<<dim3(gx(16), 4), TPB, 0, stream>>>(
      s2, 64, nullptr, 0, wb2, s4, N, 128, 128, 64, 16);
  bn(s4, g2, b2, 128, 7, 2 * sp16);

  // ---- level-2 tconvs (16 -> 32), octants ----
  mconv<1, 2, false, false><<<dim3(gx(16), 2, 8), TPB, 0, stream>>>(
      s4, 128, nullptr, 0, wb2r, r32, N, 64, 64, 128, 16);
  bn(r32, g2r, b2r, 64, 6, 2 * sp32);
  mconv<1, 2, false, false><<<dim3(gx(16), 2, 8), TPB, 0, stream>>>(
      s4, 128, nullptr, 0, wb2c, c32, N, 64, 64, 128, 16);
  bn(c32, g2c, b2c, 64, 6, 2 * sp32);

  // ---- level-1 tconvs (32 -> 64), octants ----
  mconv<1, 2, false, false><<<dim3(gx(32), 1, 8), TPB, 0, stream>>>(
      r32, 64, nullptr, 0, wb1r, r64, N, 32, 32, 64, 32);
  bn(r64, g1r, b1r, 32, 5, 2 * sp64);
  mconv<1, 2, false, false><<<dim3(gx(32), 2, 8), TPB, 0, stream>>>(
      c32, 64, s2, 64, wb1c, c64, N, 64, 64, 128, 32);
  bn(c64, g1c, b1c, 64, 6, 2 * sp64);

  // ---- level-0 stride-1 convs (no BN), LDS-staged -> fp32 NCDHW outputs ----
  mconv<0, 1, false, true><<<dim3(gx(64), 1), TPB, 0, stream>>>(
      r64, 32, nullptr, 0, wbrec, out_rec, N, 16, 16, 32, 64);
  mconv<0, 1, false, true><<<dim3(gx(64), 1), TPB, 0, stream>>>(
      c64, 64, s1, 32, wbcl, out_cl, N, 2, 16, 96, 64);
}

// Round 8
// 1121.739 us; speedup vs baseline: 3.4614x; 1.0771x over previous
//
#include <hip/hip_runtime.h>
#include <hip/hip_bf16.h>

// ---------------------------------------------------------------------------
// UNet3D dense forward, round 8: NDHWC implicit-GEMM MFMA.
//  - stride-1 convs: LDS-staged B (unchanged from R7).
//  - stride-2 tconvs: NEW quadrant form — grid.z=4 (pd,ph), both w-parities
//    in-register; LDS-staged (5,5,17)x32ci tile; 3 MFMA per 2 ds_read_b128;
//    dense full-line stores.
//  - stride-2 convs: direct-global B (small share of runtime).
// ---------------------------------------------------------------------------

using bf16 = __hip_bfloat16;
using ushort4v = __attribute__((ext_vector_type(4))) unsigned short;
using ushort8  = __attribute__((ext_vector_type(8))) unsigned short;
using short8   = __attribute__((ext_vector_type(8))) short;
using f32x4    = __attribute__((ext_vector_type(4))) float;
using float4v  = __attribute__((ext_vector_type(4))) float;

#define TPB 256

static inline int cdiv_l(long a, int b){ return (int)((a + b - 1) / b); }

__device__ __forceinline__ float b2f(unsigned short u){
  union { unsigned int i; float f; } v; v.i = ((unsigned int)u) << 16; return v.f;
}
__device__ __forceinline__ unsigned short f2b(float f){
  union { bf16 h; unsigned short u; } v; v.h = __float2bfloat16(f); return v.u;
}

// ---------------- weight repacks (bf16) ----------------
__global__ void rp_enc(const float* __restrict__ w, unsigned short* __restrict__ wb,
                       int Cin, int Cout){
  int idx = blockIdx.x * TPB + threadIdx.x;
  int tot = 27 * Cout * Cin; if (idx >= tot) return;
  int ci = idx % Cin; int t = idx / Cin; int co = t % Cout; int tap = t / Cout;
  wb[idx] = f2b(w[((long)co * Cin + ci) * 27 + tap]);
}
__global__ void rp_dec(const float* __restrict__ w, unsigned short* __restrict__ wb,
                       int Cin, int Cout, int CIP, int COP){
  int idx = blockIdx.x * TPB + threadIdx.x;
  int tot = 27 * COP * CIP; if (idx >= tot) return;
  int ci = idx % CIP; int t = idx / CIP; int co = t % COP; int tap = t / COP;
  float v = (ci < Cin && co < Cout) ? w[((long)tap * Cin + ci) * Cout + co] : 0.f;
  wb[idx] = f2b(v);
}
// conv0 tap-paired: [pp<14][co<32][k<32], k<16 -> tap 2pp ci=k; k>=16 -> tap 2pp+1
__global__ void rp_pair(const float* __restrict__ w, unsigned short* __restrict__ wb){
  int idx = blockIdx.x * TPB + threadIdx.x;
  int tot = 14 * 32 * 32; if (idx >= tot) return;
  int k = idx & 31; int t = idx >> 5; int co = t & 31; int pp = t >> 5;
  int tap = pp * 2 + (k >> 4); int ci = k & 15;
  float v = (tap < 27) ? w[((long)co * 16 + ci) * 27 + tap] : 0.f;
  wb[idx] = f2b(v);
}

// ---------------- x transpose: NCDHW fp32 -> NDHWC bf16 (C=16) ----------------
__global__ void xpose_k(const float* __restrict__ x, unsigned short* __restrict__ xt){
  __shared__ float l[16][257];
  int t = threadIdx.x;
  long p0 = (long)blockIdx.x * 256;
  int n = (int)(p0 >> 18);
  long off = p0 & 262143;
  const float* xb = x + ((long)n * 16) * 262144 + off;
#pragma unroll
  for (int c = 0; c < 16; ++c) l[c][t] = xb[(long)c * 262144 + t];
  __syncthreads();
  ushort8 u0, u1;
#pragma unroll
  for (int k = 0; k < 8; ++k){ u0[k] = f2b(l[k][t]); u1[k] = f2b(l[k + 8][t]); }
  unsigned short* o = xt + (p0 + t) * 16;
  *(ushort8*)o = u0; *(ushort8*)(o + 8) = u1;
}

// ---------------- quadrant stride-2 tconv, LDS-staged ----------------
// grid.z = quad (pd,ph); both w-parities per thread. Input half-grid tile
// 4x4x16, halo low side -> LDS (5,5,17) per 32-ci chunk.
template <int CO_TILES>
__global__ __launch_bounds__(TPB) void tconv_quad(
    const unsigned short* __restrict__ inA, int CA,
    const unsigned short* __restrict__ inB, int CB,
    const unsigned short* __restrict__ wb,
    unsigned short* __restrict__ out,
    int N, int Cout, int COP, int CIP, int G) {
  __shared__ unsigned short xs[4 * 428 * 8];   // [ciOctet][pt pad][8]
  const int tid = threadIdx.x, wv = tid >> 6, l = tid & 63, l15 = l & 15, lg = l >> 4;
  int ntW = G >> 4, ntH = G >> 2, ntD = G >> 2;
  int bx = blockIdx.x;
  int w0 = (bx % ntW) << 4; bx /= ntW;
  int h0 = (bx % ntH) << 2; bx /= ntH;
  int d0 = (bx % ntD) << 2; int n = bx / ntD;
  const int co0 = blockIdx.y * (16 * CO_TILES);
  const int quad = blockIdx.z;
  const int pd = (quad >> 1) & 1, ph = quad & 1;
  const long spin = (long)G * G * G;

  int nkd, kd_[2], dd_[2], nkh, kh_[2], dh_[2];
  if (pd){ nkd=1; kd_[0]=1; dd_[0]=0; } else { nkd=2; kd_[0]=0; dd_[0]=-1; kd_[1]=2; dd_[1]=0; }
  if (ph){ nkh=1; kh_[0]=1; dh_[0]=0; } else { nkh=2; kh_[0]=0; dh_[0]=-1; kh_[1]=2; dh_[1]=0; }

  f32x4 acc[CO_TILES][4][2];
#pragma unroll
  for (int ct = 0; ct < CO_TILES; ++ct)
#pragma unroll
    for (int j = 0; j < 4; ++j)
#pragma unroll
      for (int p = 0; p < 2; ++p) acc[ct][j][p] = (f32x4){0.f, 0.f, 0.f, 0.f};

  const int nch = CIP >> 5;
#pragma unroll 1
  for (int ch = 0; ch < nch; ++ch) {
    int c0 = ch << 5;
    const unsigned short* src; int Cs, cl_;
    if (c0 < CA){ src = inA; Cs = CA; cl_ = c0; } else { src = inB; Cs = CB; cl_ = c0 - CA; }
    const unsigned short* sb = src + (long)n * Cs * spin;
    __syncthreads();
    for (int idx = tid; idx < 4 * 425; idx += TPB) {
      int q = idx / 425, pt = idx - q * 425;
      int zw = pt % 17; int zt = pt / 17; int zh = zt % 5; int zd = zt / 5;
      int gd = d0 + zd - 1, gh = h0 + zh - 1, gw = w0 + zw - 1;
      ushort8 v = (ushort8){0,0,0,0,0,0,0,0};
      if ((unsigned)gd < (unsigned)G && (unsigned)gh < (unsigned)G && (unsigned)gw < (unsigned)G)
        v = *(const ushort8*)(sb + (((long)gd * G + gh) * G + gw) * Cs + cl_ + q * 8);
      *(ushort8*)(xs + (q * 428 + pt) * 8) = v;
    }
    __syncthreads();
#pragma unroll 1
    for (int a = 0; a < nkd; ++a) {
      int zd = wv + 1 + dd_[a];
#pragma unroll 1
      for (int b = 0; b < nkh; ++b) {
        int tapb = (kd_[a] * 3 + kh_[b]) * 3;
        const unsigned short* ap = wb + ((long)tapb * COP + co0 + l15) * CIP + c0 + lg * 8;
        long tstride = (long)COP * CIP;
        short8 A0k0 = *(const short8*)(ap);
        short8 A0k1 = *(const short8*)(ap + tstride);
        short8 A0k2 = *(const short8*)(ap + 2 * tstride);
        short8 A1k0, A1k1, A1k2;
        if (CO_TILES == 2) {
          A1k0 = *(const short8*)(ap + 16 * CIP);
          A1k1 = *(const short8*)(ap + tstride + 16 * CIP);
          A1k2 = *(const short8*)(ap + 2 * tstride + 16 * CIP);
        }
        int zh0 = 1 + dh_[b];
#pragma unroll
        for (int j = 0; j < 4; ++j) {
          int basept = (zd * 5 + (j + zh0)) * 17 + l15;
          short8 Bm = *(const short8*)(xs + (lg * 428 + basept) * 8);
          short8 B0 = *(const short8*)(xs + (lg * 428 + basept + 1) * 8);
          acc[0][j][0] = __builtin_amdgcn_mfma_f32_16x16x32_bf16(A0k0, Bm, acc[0][j][0], 0, 0, 0);
          acc[0][j][0] = __builtin_amdgcn_mfma_f32_16x16x32_bf16(A0k2, B0, acc[0][j][0], 0, 0, 0);
          acc[0][j][1] = __builtin_amdgcn_mfma_f32_16x16x32_bf16(A0k1, B0, acc[0][j][1], 0, 0, 0);
          if (CO_TILES == 2) {
            acc[1][j][0] = __builtin_amdgcn_mfma_f32_16x16x32_bf16(A1k0, Bm, acc[1][j][0], 0, 0, 0);
            acc[1][j][0] = __builtin_amdgcn_mfma_f32_16x16x32_bf16(A1k2, B0, acc[1][j][0], 0, 0, 0);
            acc[1][j][1] = __builtin_amdgcn_mfma_f32_16x16x32_bf16(A1k1, B0, acc[1][j][1], 0, 0, 0);
          }
        }
      }
    }
  }

  // ---- dense store ----
  int Gout = 2 * G; long spo = (long)Gout * Gout * Gout;
  int od = 2 * (d0 + wv) + pd;
#pragma unroll
  for (int j = 0; j < 4; ++j) {
    int oh = 2 * (h0 + j) + ph;
#pragma unroll
    for (int p = 0; p < 2; ++p) {
      int ow = 2 * (w0 + l15) + p;
      long pt = ((long)od * Gout + oh) * Gout + ow;
#pragma unroll
      for (int ct = 0; ct < CO_TILES; ++ct) {
        ushort4v pk;
#pragma unroll
        for (int r = 0; r < 4; ++r) pk[r] = f2b(acc[ct][j][p][r]);
        *(ushort4v*)(out + ((long)n * spo + pt) * Cout + co0 + ct * 16 + lg * 4) = pk;
      }
    }
  }
}

// ---------------- unified NDHWC MFMA conv (V0 stride-1 LDS / V2 stride-2) ---
template <int VARIANT, int CO_TILES, bool PAIRED, bool FOUT>
__global__ __launch_bounds__(TPB) void mconv(
    const unsigned short* __restrict__ inA, int CA,
    const unsigned short* __restrict__ inB, int CB,
    const unsigned short* __restrict__ wb,
    void* __restrict__ outv,
    int N, int Cout, int COP, int CIP, int G) {
  const int tid = threadIdx.x, wv = tid >> 6, l = tid & 63, l15 = l & 15, lg = l >> 4;
  int ntW = G >> 4, ntH = G >> 2, ntD = G >> 2;
  int bx = blockIdx.x;
  int w0 = (bx % ntW) << 4; bx /= ntW;
  int h0 = (bx % ntH) << 2; bx /= ntH;
  int d0 = (bx % ntD) << 2; int n = bx / ntD;
  const int co0 = blockIdx.y * (16 * CO_TILES);
  const int Gin = (VARIANT == 2) ? 2 * G : G;
  const long spin = (long)Gin * Gin * Gin;

  f32x4 acc[CO_TILES][4];
#pragma unroll
  for (int ct = 0; ct < CO_TILES; ++ct)
#pragma unroll
    for (int j = 0; j < 4; ++j) acc[ct][j] = (f32x4){0.f, 0.f, 0.f, 0.f};

  if constexpr (PAIRED) {
    __shared__ unsigned short xs[2 * 652 * 8];
    const unsigned short* src = inA + (long)n * 16 * spin;
    for (int idx = tid; idx < 2 * 648; idx += TPB) {
      int q = idx / 648, pt = idx - q * 648;
      int zw = pt % 18; int zt = pt / 18; int zh = zt % 6; int zd = zt / 6;
      int gd = d0 + zd - 1, gh = h0 + zh - 1, gw = w0 + zw - 1;
      ushort8 v = (ushort8){0,0,0,0,0,0,0,0};
      if ((unsigned)gd < (unsigned)G && (unsigned)gh < (unsigned)G && (unsigned)gw < (unsigned)G)
        v = *(const ushort8*)(src + (((long)gd * G + gh) * G + gw) * 16 + q * 8);
      *(ushort8*)(xs + (q * 652 + pt) * 8) = v;
    }
    __syncthreads();
#pragma unroll 1
    for (int pp = 0; pp < 14; ++pp) {
      short8 A0 = *(const short8*)(wb + ((pp * 32 + l15) * 32) + lg * 8);
      short8 A1 = *(const short8*)(wb + ((pp * 32 + 16 + l15) * 32) + lg * 8);
      int t0 = 2 * pp + (lg >> 1); if (t0 > 26) t0 = 26;
      int dd = t0 / 9 - 1, dh = (t0 / 3) % 3 - 1, dw = t0 % 3 - 1;
      int q = lg & 1;
      int zd = wv + 1 + dd;
      int base = (q * 652 + zd * 108 + (1 + dh) * 18 + 1 + l15 + dw) * 8;
#pragma unroll
      for (int j = 0; j < 4; ++j) {
        short8 B = *(const short8*)(xs + base + j * (18 * 8));
        acc[0][j] = __builtin_amdgcn_mfma_f32_16x16x32_bf16(A0, B, acc[0][j], 0, 0, 0);
        if (CO_TILES == 2)
          acc[1][j] = __builtin_amdgcn_mfma_f32_16x16x32_bf16(A1, B, acc[1][j], 0, 0, 0);
      }
    }
  } else if constexpr (VARIANT == 0) {
    __shared__ unsigned short xs[4 * 652 * 8];
    const int nch = CIP >> 5;
#pragma unroll 1
    for (int ch = 0; ch < nch; ++ch) {
      int c0 = ch << 5;
      const unsigned short* src; int Cs, cl_;
      if (c0 < CA){ src = inA; Cs = CA; cl_ = c0; } else { src = inB; Cs = CB; cl_ = c0 - CA; }
      const unsigned short* sb = src + (long)n * Cs * spin;
      __syncthreads();
      for (int idx = tid; idx < 4 * 648; idx += TPB) {
        int q = idx / 648, pt = idx - q * 648;
        int zw = pt % 18; int zt = pt / 18; int zh = zt % 6; int zd = zt / 6;
        int gd = d0 + zd - 1, gh = h0 + zh - 1, gw = w0 + zw - 1;
        ushort8 v = (ushort8){0,0,0,0,0,0,0,0};
        if ((unsigned)gd < (unsigned)G && (unsigned)gh < (unsigned)G && (unsigned)gw < (unsigned)G)
          v = *(const ushort8*)(sb + (((long)gd * G + gh) * G + gw) * Cs + cl_ + q * 8);
        *(ushort8*)(xs + (q * 652 + pt) * 8) = v;
      }
      __syncthreads();
#pragma unroll 1
      for (int a = 0; a < 3; ++a) {
        int zd = wv + a;
#pragma unroll 1
        for (int b = 0; b < 3; ++b) {
#pragma unroll
          for (int c = 0; c < 3; ++c) {
            int tap = (a * 3 + b) * 3 + c;
            const unsigned short* ap = wb + ((long)tap * COP + co0 + l15) * CIP + c0 + lg * 8;
            short8 A0 = *(const short8*)ap;
            short8 A1;
            if (CO_TILES == 2) A1 = *(const short8*)(ap + 16 * CIP);
            int base = (lg * 652 + zd * 108 + b * 18 + l15 + c) * 8;
#pragma unroll
            for (int j = 0; j < 4; ++j) {
              short8 B = *(const short8*)(xs + base + j * (18 * 8));
              acc[0][j] = __builtin_amdgcn_mfma_f32_16x16x32_bf16(A0, B, acc[0][j], 0, 0, 0);
              if (CO_TILES == 2)
                acc[1][j] = __builtin_amdgcn_mfma_f32_16x16x32_bf16(A1, B, acc[1][j], 0, 0, 0);
            }
          }
        }
      }
    }
  } else {
    // VARIANT 2: stride-2 conv, direct-global B
    const int nch = CIP >> 5;
#pragma unroll 1
    for (int ch = 0; ch < nch; ++ch) {
      int c0 = ch << 5;
      const unsigned short* src; int Cs, cl_;
      if (c0 < CA){ src = inA; Cs = CA; cl_ = c0; } else { src = inB; Cs = CB; cl_ = c0 - CA; }
      const unsigned short* sb = src + (long)n * Cs * spin;
#pragma unroll 1
      for (int a = 0; a < 3; ++a) {
        int gd = 2 * (d0 + wv) + a - 1;
        bool vd = (unsigned)gd < (unsigned)Gin;
#pragma unroll 1
        for (int b = 0; b < 3; ++b) {
#pragma unroll
          for (int c = 0; c < 3; ++c) {
            int tap = (a * 3 + b) * 3 + c;
            const unsigned short* ap = wb + ((long)tap * COP + co0 + l15) * CIP + c0 + lg * 8;
            short8 A0 = *(const short8*)ap;
            short8 A1;
            if (CO_TILES == 2) A1 = *(const short8*)(ap + 16 * CIP);
            int gw = 2 * (w0 + l15) + c - 1;
            bool vdw = vd && ((unsigned)gw < (unsigned)Gin);
#pragma unroll
            for (int j = 0; j < 4; ++j) {
              int gh = 2 * (h0 + j) + b - 1;
              short8 B = (short8){0,0,0,0,0,0,0,0};
              if (vdw && (unsigned)gh < (unsigned)Gin)
                B = *(const short8*)(sb + (((long)gd * Gin + gh) * Gin + gw) * Cs + cl_ + lg * 8);
              acc[0][j] = __builtin_amdgcn_mfma_f32_16x16x32_bf16(A0, B, acc[0][j], 0, 0, 0);
              if (CO_TILES == 2)
                acc[1][j] = __builtin_amdgcn_mfma_f32_16x16x32_bf16(A1, B, acc[1][j], 0, 0, 0);
            }
          }
        }
      }
    }
  }

  // ---- store ----
  const long spo = (long)G * G * G;
#pragma unroll
  for (int j = 0; j < 4; ++j) {
    long pt = ((long)(d0 + wv) * G + (h0 + j)) * G + (w0 + l15);
    if constexpr (!FOUT) {
      unsigned short* outp = (unsigned short*)outv;
#pragma unroll
      for (int ct = 0; ct < CO_TILES; ++ct) {
        ushort4v pk;
#pragma unroll
        for (int r = 0; r < 4; ++r) pk[r] = f2b(acc[ct][j][r]);
        *(ushort4v*)(outp + ((long)n * spo + pt) * Cout + co0 + ct * 16 + lg * 4) = pk;
      }
    } else {
      float* outp = (float*)outv;
#pragma unroll
      for (int ct = 0; ct < CO_TILES; ++ct)
#pragma unroll
        for (int r = 0; r < 4; ++r) {
          int co = co0 + ct * 16 + lg * 4 + r;
          if (co < Cout) outp[((long)(n * Cout + co)) * spo + pt] = acc[ct][j][r];
        }
    }
  }
}

// ---------------- BN stats stage 1 (channels-last) ----------------
__global__ void bn_stats1_cl(const unsigned short* __restrict__ x, float* __restrict__ part,
                             long npts, int C, int lC, int K){
  int chunk = blockIdx.x, tid = threadIdx.x;
  int c = tid & (C - 1); int pr = tid >> lC; int PR = TPB >> lC;
  float s = 0.f, q = 0.f;
  for (long p = (long)chunk * PR + pr; p < npts; p += (long)K * PR) {
    float f = b2f(x[p * C + c]); s += f; q += f * f;
  }
  __shared__ float shs[TPB], shq[TPB];
  shs[tid] = s; shq[tid] = q;
  __syncthreads();
  for (int off = TPB / 2; off >= C; off >>= 1) {
    if (tid < off) { shs[tid] += shs[tid + off]; shq[tid] += shq[tid + off]; }
    __syncthreads();
  }
  if (tid < C) { part[((long)tid * K + chunk) * 2] = shs[tid]; part[((long)tid * K + chunk) * 2 + 1] = shq[tid]; }
}

// ---------------- BN stats stage 2 ----------------
__global__ void bn_stats2_k(const float* __restrict__ part, const float* __restrict__ g,
                            const float* __restrict__ b, float* __restrict__ scale,
                            float* __restrict__ shift, int C, int K, float inv_cnt) {
  int c = blockIdx.x * blockDim.x + threadIdx.x;
  if (c >= C) return;
  float s = 0.f, q = 0.f;
  for (int k = 0; k < K; ++k) { s += part[((long)c * K + k) * 2]; q += part[((long)c * K + k) * 2 + 1]; }
  float m = s * inv_cnt, v = q * inv_cnt - m * m;
  float rs = rsqrtf(v + 1e-5f) * g[c];
  scale[c] = rs;
  shift[c] = b[c] - m * rs;
}

// ---------------- BN apply + ReLU (channels-last, vectorized) ----------------
__global__ void bn_relu_cl(unsigned short* __restrict__ x, const float* __restrict__ sc,
                           const float* __restrict__ sh, int C, long tot8){
  long i8 = (long)blockIdx.x * TPB + threadIdx.x;
  if (i8 >= tot8) return;
  long e = i8 * 8;
  int c0 = (int)(e & (C - 1));
  float4v s0 = *(const float4v*)(sc + c0), s1 = *(const float4v*)(sc + c0 + 4);
  float4v h0 = *(const float4v*)(sh + c0), h1 = *(const float4v*)(sh + c0 + 4);
  ushort8 v = *(ushort8*)(x + e);
  ushort8 r;
#pragma unroll
  for (int j = 0; j < 4; ++j) {
    float y = b2f(v[j]) * s0[j] + h0[j];
    r[j] = f2b(y > 0.f ? y : 0.f);
  }
#pragma unroll
  for (int j = 0; j < 4; ++j) {
    float y = b2f(v[j + 4]) * s1[j] + h1[j];
    r[j + 4] = f2b(y > 0.f ? y : 0.f);
  }
  *(ushort8*)(x + e) = r;
}

extern "C" void kernel_launch(void* const* d_in, const int* in_sizes, int n_in,
                              void* d_out, int out_size, void* d_ws, size_t ws_size,
                              hipStream_t stream) {
  const float* x    = (const float*)d_in[0];
  const float* w0   = (const float*)d_in[1];
  const float* g0   = (const float*)d_in[2];
  const float* b0   = (const float*)d_in[3];
  const float* w1   = (const float*)d_in[4];
  const float* g1   = (const float*)d_in[5];
  const float* b1   = (const float*)d_in[6];
  const float* w2   = (const float*)d_in[7];
  const float* g2   = (const float*)d_in[8];
  const float* b2   = (const float*)d_in[9];
  const float* wt2r = (const float*)d_in[10];
  const float* g2r  = (const float*)d_in[11];
  const float* b2r  = (const float*)d_in[12];
  const float* wt1r = (const float*)d_in[13];
  const float* g1r  = (const float*)d_in[14];
  const float* b1r  = (const float*)d_in[15];
  const float* wt0r = (const float*)d_in[16];
  const float* wt2c = (const float*)d_in[17];
  const float* g2c  = (const float*)d_in[18];
  const float* b2c  = (const float*)d_in[19];
  const float* wt1c = (const float*)d_in[20];
  const float* g1c  = (const float*)d_in[21];
  const float* b1c  = (const float*)d_in[22];
  const float* wt0c = (const float*)d_in[23];

  const int N = 2;
  const long sp64 = 262144, sp32 = 32768, sp16 = 4096;
  const int K = 256;  // bn chunks

  // ---- workspace (ushort units), all activations NDHWC bf16 ----
  unsigned short* W = (unsigned short*)d_ws;
  unsigned short* s1   = W;                       // [2*sp64][32]
  unsigned short* s2   = s1  + 16777216;          // [2*sp32][64]
  unsigned short* s4   = s2  + 4194304;           // [2*sp16][128]
  unsigned short* r32  = s4  + 1048576;           // [2*sp32][64]
  unsigned short* c32  = r32 + 4194304;           // [2*sp32][64]
  unsigned short* r64  = c32 + 4194304;           // [2*sp64][32]
  unsigned short* xt   = r64;                     // alias (dead after conv0)
  unsigned short* c64  = r64 + 16777216;          // [2*sp64][64]
  unsigned short* wb0p = c64 + 33554432;          // 14*32*32
  unsigned short* wb1  = wb0p + 14336;            // 27*64*32
  unsigned short* wb2  = wb1  + 55296;            // 27*128*64
  unsigned short* wb2r = wb2  + 221184;           // 27*64*128
  unsigned short* wb2c = wb2r + 221184;
  unsigned short* wb1r = wb2c + 221184;           // 27*32*64
  unsigned short* wb1c = wb1r + 55296;            // 27*64*128
  unsigned short* wbrec= wb1c + 221184;           // 27*16*32
  unsigned short* wbcl = wbrec+ 13824;            // 27*16*96
  float* part = (float*)(wbcl + 41472);
  float* bsc  = part + 128L * K * 2;
  float* bsh  = bsc + 128;

  float* out_cl  = (float*)d_out;                 // [2][2][64^3] NCDHW
  float* out_rec = (float*)d_out + 2L * 2 * sp64; // [2][16][64^3]

  // ---- weight repacks ----
  rp_pair<<<cdiv_l(14L*32*32, TPB), TPB, 0, stream>>>(w0, wb0p);
  rp_enc<<<cdiv_l(27L*64*32, TPB), TPB, 0, stream>>>(w1, wb1, 32, 64);
  rp_enc<<<cdiv_l(27L*128*64, TPB), TPB, 0, stream>>>(w2, wb2, 64, 128);
  rp_dec<<<cdiv_l(27L*64*128, TPB), TPB, 0, stream>>>(wt2r, wb2r, 128, 64, 128, 64);
  rp_dec<<<cdiv_l(27L*64*128, TPB), TPB, 0, stream>>>(wt2c, wb2c, 128, 64, 128, 64);
  rp_dec<<<cdiv_l(27L*32*64, TPB), TPB, 0, stream>>>(wt1r, wb1r, 64, 32, 64, 32);
  rp_dec<<<cdiv_l(27L*64*128, TPB), TPB, 0, stream>>>(wt1c, wb1c, 128, 64, 128, 64);
  rp_dec<<<cdiv_l(27L*16*32, TPB), TPB, 0, stream>>>(wt0r, wbrec, 32, 16, 32, 16);
  rp_dec<<<cdiv_l(27L*16*96, TPB), TPB, 0, stream>>>(wt0c, wbcl, 96, 2, 96, 16);

  // ---- x -> NDHWC bf16 ----
  xpose_k<<<2048, TPB, 0, stream>>>(x, xt);

  auto bn = [&](unsigned short* t, const float* g, const float* b, int C, int lC, long npts) {
    bn_stats1_cl<<<K, TPB, 0, stream>>>(t, part, npts, C, lC, K);
    bn_stats2_k<<<1, 128, 0, stream>>>(part, g, b, bsc, bsh, C, K, 1.f / (float)(npts));
    long tot8 = npts * C / 8;
    bn_relu_cl<<<cdiv_l(tot8, TPB), TPB, 0, stream>>>(t, bsc, bsh, C, tot8);
  };

  auto gx = [&](int G){ return (unsigned)(N * (G >> 2) * (G >> 2) * (G >> 4)); };

  // ---- encoder ----
  mconv<0, 2, true, false><<<dim3(gx(64), 1), TPB, 0, stream>>>(
      xt, 16, nullptr, 0, wb0p, s1, N, 32, 32, 32, 64);
  bn(s1, g0, b0, 32, 5, 2 * sp64);
  mconv<2, 2, false, false><<<dim3(gx(32), 2), TPB, 0, stream>>>(
      s1, 32, nullptr, 0, wb1, s2, N, 64, 64, 32, 32);
  bn(s2, g1, b1, 64, 6, 2 * sp32);
  mconv<2, 2, false, false><<<dim3(gx(16), 4), TPB, 0, stream>>>(
      s2, 64, nullptr, 0, wb2, s4, N, 128, 128, 64, 16);
  bn(s4, g2, b2, 128, 7, 2 * sp16);

  // ---- level-2 tconvs (16 -> 32), quadrants ----
  tconv_quad<2><<<dim3(gx(16), 2, 4), TPB, 0, stream>>>(
      s4, 128, nullptr, 0, wb2r, r32, N, 64, 64, 128, 16);
  bn(r32, g2r, b2r, 64, 6, 2 * sp32);
  tconv_quad<2><<<dim3(gx(16), 2, 4), TPB, 0, stream>>>(
      s4, 128, nullptr, 0, wb2c, c32, N, 64, 64, 128, 16);
  bn(c32, g2c, b2c, 64, 6, 2 * sp32);

  // ---- level-1 tconvs (32 -> 64), quadrants ----
  tconv_quad<2><<<dim3(gx(32), 1, 4), TPB, 0, stream>>>(
      r32, 64, nullptr, 0, wb1r, r64, N, 32, 32, 64, 32);
  bn(r64, g1r, b1r, 32, 5, 2 * sp64);
  tconv_quad<2><<<dim3(gx(32), 2, 4), TPB, 0, stream>>>(
      c32, 64, s2, 64, wb1c, c64, N, 64, 64, 128, 32);
  bn(c64, g1c, b1c, 64, 6, 2 * sp64);

  // ---- level-0 stride-1 convs (no BN), LDS-staged -> fp32 NCDHW outputs ----
  mconv<0, 1, false, true><<<dim3(gx(64), 1), TPB, 0, stream>>>(
      r64, 32, nullptr, 0, wbrec, out_rec, N, 16, 16, 32, 64);
  mconv<0, 1, false, true><<<dim3(gx(64), 1), TPB, 0, stream>>>(
      c64, 64, s1, 32, wbcl, out_cl, N, 2, 16, 96, 64);
}

// Round 9
// 1090.031 us; speedup vs baseline: 3.5621x; 1.0291x over previous
//
#include <hip/hip_runtime.h>
#include <hip/hip_bf16.h>

// ---------------------------------------------------------------------------
// UNet3D dense forward, round 9: NDHWC implicit-GEMM MFMA.
//  - LDS plane stride -> multiple of 128B (conflict-free b128 reads).
//  - V0 stride-1 conv: s=b+j row-sharing (2x fewer ds_reads), A hoisted.
//  - tconv1c: CO_TILES=4, y=1 (stage once, 6:1 MFMA:ds_read).
// ---------------------------------------------------------------------------

using bf16 = __hip_bfloat16;
using ushort4v = __attribute__((ext_vector_type(4))) unsigned short;
using ushort8  = __attribute__((ext_vector_type(8))) unsigned short;
using short8   = __attribute__((ext_vector_type(8))) short;
using f32x4    = __attribute__((ext_vector_type(4))) float;
using float4v  = __attribute__((ext_vector_type(4))) float;

#define TPB 256

static inline int cdiv_l(long a, int b){ return (int)((a + b - 1) / b); }

__device__ __forceinline__ float b2f(unsigned short u){
  union { unsigned int i; float f; } v; v.i = ((unsigned int)u) << 16; return v.f;
}
__device__ __forceinline__ unsigned short f2b(float f){
  union { bf16 h; unsigned short u; } v; v.h = __float2bfloat16(f); return v.u;
}

// ---------------- weight repacks (bf16) ----------------
__global__ void rp_enc(const float* __restrict__ w, unsigned short* __restrict__ wb,
                       int Cin, int Cout){
  int idx = blockIdx.x * TPB + threadIdx.x;
  int tot = 27 * Cout * Cin; if (idx >= tot) return;
  int ci = idx % Cin; int t = idx / Cin; int co = t % Cout; int tap = t / Cout;
  wb[idx] = f2b(w[((long)co * Cin + ci) * 27 + tap]);
}
__global__ void rp_dec(const float* __restrict__ w, unsigned short* __restrict__ wb,
                       int Cin, int Cout, int CIP, int COP){
  int idx = blockIdx.x * TPB + threadIdx.x;
  int tot = 27 * COP * CIP; if (idx >= tot) return;
  int ci = idx % CIP; int t = idx / CIP; int co = t % COP; int tap = t / COP;
  float v = (ci < Cin && co < Cout) ? w[((long)tap * Cin + ci) * Cout + co] : 0.f;
  wb[idx] = f2b(v);
}
// conv0 tap-paired: [pp<14][co<32][k<32]
__global__ void rp_pair(const float* __restrict__ w, unsigned short* __restrict__ wb){
  int idx = blockIdx.x * TPB + threadIdx.x;
  int tot = 14 * 32 * 32; if (idx >= tot) return;
  int k = idx & 31; int t = idx >> 5; int co = t & 31; int pp = t >> 5;
  int tap = pp * 2 + (k >> 4); int ci = k & 15;
  float v = (tap < 27) ? w[((long)co * 16 + ci) * 27 + tap] : 0.f;
  wb[idx] = f2b(v);
}

// ---------------- x transpose: NCDHW fp32 -> NDHWC bf16 (C=16) ----------------
__global__ void xpose_k(const float* __restrict__ x, unsigned short* __restrict__ xt){
  __shared__ float l[16][257];
  int t = threadIdx.x;
  long p0 = (long)blockIdx.x * 256;
  int n = (int)(p0 >> 18);
  long off = p0 & 262143;
  const float* xb = x + ((long)n * 16) * 262144 + off;
#pragma unroll
  for (int c = 0; c < 16; ++c) l[c][t] = xb[(long)c * 262144 + t];
  __syncthreads();
  ushort8 u0, u1;
#pragma unroll
  for (int k = 0; k < 8; ++k){ u0[k] = f2b(l[k][t]); u1[k] = f2b(l[k + 8][t]); }
  unsigned short* o = xt + (p0 + t) * 16;
  *(ushort8*)o = u0; *(ushort8*)(o + 8) = u1;
}

// ---------------- quadrant stride-2 tconv, LDS-staged ----------------
// grid.z = quad (pd,ph); both w-parities per thread. LDS plane 432 (aligned).
template <int CO_TILES>
__global__ __launch_bounds__(TPB, 2) void tconv_quad(
    const unsigned short* __restrict__ inA, int CA,
    const unsigned short* __restrict__ inB, int CB,
    const unsigned short* __restrict__ wb,
    unsigned short* __restrict__ out,
    int N, int Cout, int COP, int CIP, int G) {
  __shared__ unsigned short xs[4 * 432 * 8];
  const int tid = threadIdx.x, wv = tid >> 6, l = tid & 63, l15 = l & 15, lg = l >> 4;
  int ntW = G >> 4, ntH = G >> 2, ntD = G >> 2;
  int bx = blockIdx.x;
  int w0 = (bx % ntW) << 4; bx /= ntW;
  int h0 = (bx % ntH) << 2; bx /= ntH;
  int d0 = (bx % ntD) << 2; int n = bx / ntD;
  const int co0 = blockIdx.y * (16 * CO_TILES);
  const int quad = blockIdx.z;
  const int pd = (quad >> 1) & 1, ph = quad & 1;
  const long spin = (long)G * G * G;

  int nkd, kd_[2], dd_[2], nkh, kh_[2], dh_[2];
  if (pd){ nkd=1; kd_[0]=1; dd_[0]=0; } else { nkd=2; kd_[0]=0; dd_[0]=-1; kd_[1]=2; dd_[1]=0; }
  if (ph){ nkh=1; kh_[0]=1; dh_[0]=0; } else { nkh=2; kh_[0]=0; dh_[0]=-1; kh_[1]=2; dh_[1]=0; }

  f32x4 acc[CO_TILES][4][2];
#pragma unroll
  for (int ct = 0; ct < CO_TILES; ++ct)
#pragma unroll
    for (int j = 0; j < 4; ++j)
#pragma unroll
      for (int p = 0; p < 2; ++p) acc[ct][j][p] = (f32x4){0.f, 0.f, 0.f, 0.f};

  const int nch = CIP >> 5;
#pragma unroll 1
  for (int ch = 0; ch < nch; ++ch) {
    int c0 = ch << 5;
    const unsigned short* src; int Cs, cl_;
    if (c0 < CA){ src = inA; Cs = CA; cl_ = c0; } else { src = inB; Cs = CB; cl_ = c0 - CA; }
    const unsigned short* sb = src + (long)n * Cs * spin;
    __syncthreads();
    for (int idx = tid; idx < 4 * 425; idx += TPB) {
      int q = idx / 425, pt = idx - q * 425;
      int zw = pt % 17; int zt = pt / 17; int zh = zt % 5; int zd = zt / 5;
      int gd = d0 + zd - 1, gh = h0 + zh - 1, gw = w0 + zw - 1;
      ushort8 v = (ushort8){0,0,0,0,0,0,0,0};
      if ((unsigned)gd < (unsigned)G && (unsigned)gh < (unsigned)G && (unsigned)gw < (unsigned)G)
        v = *(const ushort8*)(sb + (((long)gd * G + gh) * G + gw) * Cs + cl_ + q * 8);
      *(ushort8*)(xs + (q * 432 + pt) * 8) = v;
    }
    __syncthreads();
#pragma unroll 1
    for (int a = 0; a < nkd; ++a) {
      int zd = wv + 1 + dd_[a];
#pragma unroll 1
      for (int b = 0; b < nkh; ++b) {
        int tapb = (kd_[a] * 3 + kh_[b]) * 3;
        const unsigned short* ap = wb + ((long)tapb * COP + co0 + l15) * CIP + c0 + lg * 8;
        long tstride = (long)COP * CIP;
        short8 Ak0[CO_TILES], Ak1[CO_TILES], Ak2[CO_TILES];
#pragma unroll
        for (int ct = 0; ct < CO_TILES; ++ct) {
          Ak0[ct] = *(const short8*)(ap + ct * 16 * CIP);
          Ak1[ct] = *(const short8*)(ap + tstride + ct * 16 * CIP);
          Ak2[ct] = *(const short8*)(ap + 2 * tstride + ct * 16 * CIP);
        }
        int zh0 = 1 + dh_[b];
#pragma unroll
        for (int j = 0; j < 4; ++j) {
          int basept = (zd * 5 + (j + zh0)) * 17 + l15;
          short8 Bm = *(const short8*)(xs + (lg * 432 + basept) * 8);
          short8 B0 = *(const short8*)(xs + (lg * 432 + basept + 1) * 8);
#pragma unroll
          for (int ct = 0; ct < CO_TILES; ++ct) {
            acc[ct][j][0] = __builtin_amdgcn_mfma_f32_16x16x32_bf16(Ak0[ct], Bm, acc[ct][j][0], 0, 0, 0);
            acc[ct][j][0] = __builtin_amdgcn_mfma_f32_16x16x32_bf16(Ak2[ct], B0, acc[ct][j][0], 0, 0, 0);
            acc[ct][j][1] = __builtin_amdgcn_mfma_f32_16x16x32_bf16(Ak1[ct], B0, acc[ct][j][1], 0, 0, 0);
          }
        }
      }
    }
  }

  // ---- dense store ----
  int Gout = 2 * G; long spo = (long)Gout * Gout * Gout;
  int od = 2 * (d0 + wv) + pd;
#pragma unroll
  for (int j = 0; j < 4; ++j) {
    int oh = 2 * (h0 + j) + ph;
#pragma unroll
    for (int p = 0; p < 2; ++p) {
      int ow = 2 * (w0 + l15) + p;
      long pt = ((long)od * Gout + oh) * Gout + ow;
#pragma unroll
      for (int ct = 0; ct < CO_TILES; ++ct) {
        ushort4v pk;
#pragma unroll
        for (int r = 0; r < 4; ++r) pk[r] = f2b(acc[ct][j][p][r]);
        *(ushort4v*)(out + ((long)n * spo + pt) * Cout + co0 + ct * 16 + lg * 4) = pk;
      }
    }
  }
}

// ---------------- unified NDHWC MFMA conv (V0 stride-1 LDS / V2 stride-2) ---
template <int VARIANT, int CO_TILES, bool PAIRED, bool FOUT>
__global__ __launch_bounds__(TPB) void mconv(
    const unsigned short* __restrict__ inA, int CA,
    const unsigned short* __restrict__ inB, int CB,
    const unsigned short* __restrict__ wb,
    void* __restrict__ outv,
    int N, int Cout, int COP, int CIP, int G) {
  const int tid = threadIdx.x, wv = tid >> 6, l = tid & 63, l15 = l & 15, lg = l >> 4;
  int ntW = G >> 4, ntH = G >> 2, ntD = G >> 2;
  int bx = blockIdx.x;
  int w0 = (bx % ntW) << 4; bx /= ntW;
  int h0 = (bx % ntH) << 2; bx /= ntH;
  int d0 = (bx % ntD) << 2; int n = bx / ntD;
  const int co0 = blockIdx.y * (16 * CO_TILES);
  const int Gin = (VARIANT == 2) ? 2 * G : G;
  const long spin = (long)Gin * Gin * Gin;

  f32x4 acc[CO_TILES][4];
#pragma unroll
  for (int ct = 0; ct < CO_TILES; ++ct)
#pragma unroll
    for (int j = 0; j < 4; ++j) acc[ct][j] = (f32x4){0.f, 0.f, 0.f, 0.f};

  if constexpr (PAIRED) {
    __shared__ unsigned short xs[2 * 656 * 8];
    const unsigned short* src = inA + (long)n * 16 * spin;
    for (int idx = tid; idx < 2 * 648; idx += TPB) {
      int q = idx / 648, pt = idx - q * 648;
      int zw = pt % 18; int zt = pt / 18; int zh = zt % 6; int zd = zt / 6;
      int gd = d0 + zd - 1, gh = h0 + zh - 1, gw = w0 + zw - 1;
      ushort8 v = (ushort8){0,0,0,0,0,0,0,0};
      if ((unsigned)gd < (unsigned)G && (unsigned)gh < (unsigned)G && (unsigned)gw < (unsigned)G)
        v = *(const ushort8*)(src + (((long)gd * G + gh) * G + gw) * 16 + q * 8);
      *(ushort8*)(xs + (q * 656 + pt) * 8) = v;
    }
    __syncthreads();
#pragma unroll 1
    for (int pp = 0; pp < 14; ++pp) {
      short8 A0 = *(const short8*)(wb + ((pp * 32 + l15) * 32) + lg * 8);
      short8 A1 = *(const short8*)(wb + ((pp * 32 + 16 + l15) * 32) + lg * 8);
      int t0 = 2 * pp + (lg >> 1); if (t0 > 26) t0 = 26;
      int dd = t0 / 9 - 1, dh = (t0 / 3) % 3 - 1, dw = t0 % 3 - 1;
      int q = lg & 1;
      int zd = wv + 1 + dd;
      int base = (q * 656 + zd * 108 + (1 + dh) * 18 + 1 + l15 + dw) * 8;
#pragma unroll
      for (int j = 0; j < 4; ++j) {
        short8 B = *(const short8*)(xs + base + j * (18 * 8));
        acc[0][j] = __builtin_amdgcn_mfma_f32_16x16x32_bf16(A0, B, acc[0][j], 0, 0, 0);
        if (CO_TILES == 2)
          acc[1][j] = __builtin_amdgcn_mfma_f32_16x16x32_bf16(A1, B, acc[1][j], 0, 0, 0);
      }
    }
  } else if constexpr (VARIANT == 0) {
    // stride-1 conv: s=b+j row-sharing. 3 ds_reads feed up to 9 MFMAs.
    __shared__ unsigned short xs[4 * 656 * 8];
    const int nch = CIP >> 5;
#pragma unroll 1
    for (int ch = 0; ch < nch; ++ch) {
      int c0 = ch << 5;
      const unsigned short* src; int Cs, cl_;
      if (c0 < CA){ src = inA; Cs = CA; cl_ = c0; } else { src = inB; Cs = CB; cl_ = c0 - CA; }
      const unsigned short* sb = src + (long)n * Cs * spin;
      __syncthreads();
      for (int idx = tid; idx < 4 * 648; idx += TPB) {
        int q = idx / 648, pt = idx - q * 648;
        int zw = pt % 18; int zt = pt / 18; int zh = zt % 6; int zd = zt / 6;
        int gd = d0 + zd - 1, gh = h0 + zh - 1, gw = w0 + zw - 1;
        ushort8 v = (ushort8){0,0,0,0,0,0,0,0};
        if ((unsigned)gd < (unsigned)G && (unsigned)gh < (unsigned)G && (unsigned)gw < (unsigned)G)
          v = *(const ushort8*)(sb + (((long)gd * G + gh) * G + gw) * Cs + cl_ + q * 8);
        *(ushort8*)(xs + (q * 656 + pt) * 8) = v;
      }
      __syncthreads();
#pragma unroll 1
      for (int a = 0; a < 3; ++a) {
        int zd = wv + a;
        // hoist A taps for this d-plane
        short8 A0[3][3], A1[3][3];
#pragma unroll
        for (int b = 0; b < 3; ++b)
#pragma unroll
          for (int c = 0; c < 3; ++c) {
            int tap = (a * 3 + b) * 3 + c;
            const unsigned short* ap = wb + ((long)tap * COP + co0 + l15) * CIP + c0 + lg * 8;
            A0[b][c] = *(const short8*)ap;
            if (CO_TILES == 2) A1[b][c] = *(const short8*)(ap + 16 * CIP);
          }
#pragma unroll
        for (int s = 0; s < 6; ++s) {
          int rb = (lg * 656 + zd * 108 + s * 18 + l15) * 8;
          short8 B0 = *(const short8*)(xs + rb);
          short8 B1 = *(const short8*)(xs + rb + 8);
          short8 B2 = *(const short8*)(xs + rb + 16);
#pragma unroll
          for (int b = 0; b < 3; ++b) {
            int j = s - b;
            if (j >= 0 && j < 4) {
              acc[0][j] = __builtin_amdgcn_mfma_f32_16x16x32_bf16(A0[b][0], B0, acc[0][j], 0, 0, 0);
              acc[0][j] = __builtin_amdgcn_mfma_f32_16x16x32_bf16(A0[b][1], B1, acc[0][j], 0, 0, 0);
              acc[0][j] = __builtin_amdgcn_mfma_f32_16x16x32_bf16(A0[b][2], B2, acc[0][j], 0, 0, 0);
              if (CO_TILES == 2) {
                acc[1][j] = __builtin_amdgcn_mfma_f32_16x16x32_bf16(A1[b][0], B0, acc[1][j], 0, 0, 0);
                acc[1][j] = __builtin_amdgcn_mfma_f32_16x16x32_bf16(A1[b][1], B1, acc[1][j], 0, 0, 0);
                acc[1][j] = __builtin_amdgcn_mfma_f32_16x16x32_bf16(A1[b][2], B2, acc[1][j], 0, 0, 0);
              }
            }
          }
        }
      }
    }
  } else {
    // VARIANT 2: stride-2 conv, direct-global B
    const int nch = CIP >> 5;
#pragma unroll 1
    for (int ch = 0; ch < nch; ++ch) {
      int c0 = ch << 5;
      const unsigned short* src; int Cs, cl_;
      if (c0 < CA){ src = inA; Cs = CA; cl_ = c0; } else { src = inB; Cs = CB; cl_ = c0 - CA; }
      const unsigned short* sb = src + (long)n * Cs * spin;
#pragma unroll 1
      for (int a = 0; a < 3; ++a) {
        int gd = 2 * (d0 + wv) + a - 1;
        bool vd = (unsigned)gd < (unsigned)Gin;
#pragma unroll 1
        for (int b = 0; b < 3; ++b) {
#pragma unroll
          for (int c = 0; c < 3; ++c) {
            int tap = (a * 3 + b) * 3 + c;
            const unsigned short* ap = wb + ((long)tap * COP + co0 + l15) * CIP + c0 + lg * 8;
            short8 A0 = *(const short8*)ap;
            short8 A1;
            if (CO_TILES == 2) A1 = *(const short8*)(ap + 16 * CIP);
            int gw = 2 * (w0 + l15) + c - 1;
            bool vdw = vd && ((unsigned)gw < (unsigned)Gin);
#pragma unroll
            for (int j = 0; j < 4; ++j) {
              int gh = 2 * (h0 + j) + b - 1;
              short8 B = (short8){0,0,0,0,0,0,0,0};
              if (vdw && (unsigned)gh < (unsigned)Gin)
                B = *(const short8*)(sb + (((long)gd * Gin + gh) * Gin + gw) * Cs + cl_ + lg * 8);
              acc[0][j] = __builtin_amdgcn_mfma_f32_16x16x32_bf16(A0, B, acc[0][j], 0, 0, 0);
              if (CO_TILES == 2)
                acc[1][j] = __builtin_amdgcn_mfma_f32_16x16x32_bf16(A1, B, acc[1][j], 0, 0, 0);
            }
          }
        }
      }
    }
  }

  // ---- store ----
  const long spo = (long)G * G * G;
#pragma unroll
  for (int j = 0; j < 4; ++j) {
    long pt = ((long)(d0 + wv) * G + (h0 + j)) * G + (w0 + l15);
    if constexpr (!FOUT) {
      unsigned short* outp = (unsigned short*)outv;
#pragma unroll
      for (int ct = 0; ct < CO_TILES; ++ct) {
        ushort4v pk;
#pragma unroll
        for (int r = 0; r < 4; ++r) pk[r] = f2b(acc[ct][j][r]);
        *(ushort4v*)(outp + ((long)n * spo + pt) * Cout + co0 + ct * 16 + lg * 4) = pk;
      }
    } else {
      float* outp = (float*)outv;
#pragma unroll
      for (int ct = 0; ct < CO_TILES; ++ct)
#pragma unroll
        for (int r = 0; r < 4; ++r) {
          int co = co0 + ct * 16 + lg * 4 + r;
          if (co < Cout) outp[((long)(n * Cout + co)) * spo + pt] = acc[ct][j][r];
        }
    }
  }
}

// ---------------- BN stats stage 1 (channels-last) ----------------
__global__ void bn_stats1_cl(const unsigned short* __restrict__ x, float* __restrict__ part,
                             long npts, int C, int lC, int K){
  int chunk = blockIdx.x, tid = threadIdx.x;
  int c = tid & (C - 1); int pr = tid >> lC; int PR = TPB >> lC;
  float s = 0.f, q = 0.f;
  for (long p = (long)chunk * PR + pr; p < npts; p += (long)K * PR) {
    float f = b2f(x[p * C + c]); s += f; q += f * f;
  }
  __shared__ float shs[TPB], shq[TPB];
  shs[tid] = s; shq[tid] = q;
  __syncthreads();
  for (int off = TPB / 2; off >= C; off >>= 1) {
    if (tid < off) { shs[tid] += shs[tid + off]; shq[tid] += shq[tid + off]; }
    __syncthreads();
  }
  if (tid < C) { part[((long)tid * K + chunk) * 2] = shs[tid]; part[((long)tid * K + chunk) * 2 + 1] = shq[tid]; }
}

// ---------------- BN stats stage 2 ----------------
__global__ void bn_stats2_k(const float* __restrict__ part, const float* __restrict__ g,
                            const float* __restrict__ b, float* __restrict__ scale,
                            float* __restrict__ shift, int C, int K, float inv_cnt) {
  int c = blockIdx.x * blockDim.x + threadIdx.x;
  if (c >= C) return;
  float s = 0.f, q = 0.f;
  for (int k = 0; k < K; ++k) { s += part[((long)c * K + k) * 2]; q += part[((long)c * K + k) * 2 + 1]; }
  float m = s * inv_cnt, v = q * inv_cnt - m * m;
  float rs = rsqrtf(v + 1e-5f) * g[c];
  scale[c] = rs;
  shift[c] = b[c] - m * rs;
}

// ---------------- BN apply + ReLU (channels-last, vectorized) ----------------
__global__ void bn_relu_cl(unsigned short* __restrict__ x, const float* __restrict__ sc,
                           const float* __restrict__ sh, int C, long tot8){
  long i8 = (long)blockIdx.x * TPB + threadIdx.x;
  if (i8 >= tot8) return;
  long e = i8 * 8;
  int c0 = (int)(e & (C - 1));
  float4v s0 = *(const float4v*)(sc + c0), s1 = *(const float4v*)(sc + c0 + 4);
  float4v h0 = *(const float4v*)(sh + c0), h1 = *(const float4v*)(sh + c0 + 4);
  ushort8 v = *(ushort8*)(x + e);
  ushort8 r;
#pragma unroll
  for (int j = 0; j < 4; ++j) {
    float y = b2f(v[j]) * s0[j] + h0[j];
    r[j] = f2b(y > 0.f ? y : 0.f);
  }
#pragma unroll
  for (int j = 0; j < 4; ++j) {
    float y = b2f(v[j + 4]) * s1[j] + h1[j];
    r[j + 4] = f2b(y > 0.f ? y : 0.f);
  }
  *(ushort8*)(x + e) = r;
}

extern "C" void kernel_launch(void* const* d_in, const int* in_sizes, int n_in,
                              void* d_out, int out_size, void* d_ws, size_t ws_size,
                              hipStream_t stream) {
  const float* x    = (const float*)d_in[0];
  const float* w0   = (const float*)d_in[1];
  const float* g0   = (const float*)d_in[2];
  const float* b0   = (const float*)d_in[3];
  const float* w1   = (const float*)d_in[4];
  const float* g1   = (const float*)d_in[5];
  const float* b1   = (const float*)d_in[6];
  const float* w2   = (const float*)d_in[7];
  const float* g2   = (const float*)d_in[8];
  const float* b2   = (const float*)d_in[9];
  const float* wt2r = (const float*)d_in[10];
  const float* g2r  = (const float*)d_in[11];
  const float* b2r  = (const float*)d_in[12];
  const float* wt1r = (const float*)d_in[13];
  const float* g1r  = (const float*)d_in[14];
  const float* b1r  = (const float*)d_in[15];
  const float* wt0r = (const float*)d_in[16];
  const float* wt2c = (const float*)d_in[17];
  const float* g2c  = (const float*)d_in[18];
  const float* b2c  = (const float*)d_in[19];
  const float* wt1c = (const float*)d_in[20];
  const float* g1c  = (const float*)d_in[21];
  const float* b1c  = (const float*)d_in[22];
  const float* wt0c = (const float*)d_in[23];

  const int N = 2;
  const long sp64 = 262144, sp32 = 32768, sp16 = 4096;
  const int K = 256;  // bn chunks

  // ---- workspace (ushort units), all activations NDHWC bf16 ----
  unsigned short* W = (unsigned short*)d_ws;
  unsigned short* s1   = W;                       // [2*sp64][32]
  unsigned short* s2   = s1  + 16777216;          // [2*sp32][64]
  unsigned short* s4   = s2  + 4194304;           // [2*sp16][128]
  unsigned short* r32  = s4  + 1048576;           // [2*sp32][64]
  unsigned short* c32  = r32 + 4194304;           // [2*sp32][64]
  unsigned short* r64  = c32 + 4194304;           // [2*sp64][32]
  unsigned short* xt   = r64;                     // alias (dead after conv0)
  unsigned short* c64  = r64 + 16777216;          // [2*sp64][64]
  unsigned short* wb0p = c64 + 33554432;          // 14*32*32
  unsigned short* wb1  = wb0p + 14336;            // 27*64*32
  unsigned short* wb2  = wb1  + 55296;            // 27*128*64
  unsigned short* wb2r = wb2  + 221184;           // 27*64*128
  unsigned short* wb2c = wb2r + 221184;
  unsigned short* wb1r = wb2c + 221184;           // 27*32*64
  unsigned short* wb1c = wb1r + 55296;            // 27*64*128
  unsigned short* wbrec= wb1c + 221184;           // 27*16*32
  unsigned short* wbcl = wbrec+ 13824;            // 27*16*96
  float* part = (float*)(wbcl + 41472);
  float* bsc  = part + 128L * K * 2;
  float* bsh  = bsc + 128;

  float* out_cl  = (float*)d_out;                 // [2][2][64^3] NCDHW
  float* out_rec = (float*)d_out + 2L * 2 * sp64; // [2][16][64^3]

  // ---- weight repacks ----
  rp_pair<<<cdiv_l(14L*32*32, TPB), TPB, 0, stream>>>(w0, wb0p);
  rp_enc<<<cdiv_l(27L*64*32, TPB), TPB, 0, stream>>>(w1, wb1, 32, 64);
  rp_enc<<<cdiv_l(27L*128*64, TPB), TPB, 0, stream>>>(w2, wb2, 64, 128);
  rp_dec<<<cdiv_l(27L*64*128, TPB), TPB, 0, stream>>>(wt2r, wb2r, 128, 64, 128, 64);
  rp_dec<<<cdiv_l(27L*64*128, TPB), TPB, 0, stream>>>(wt2c, wb2c, 128, 64, 128, 64);
  rp_dec<<<cdiv_l(27L*32*64, TPB), TPB, 0, stream>>>(wt1r, wb1r, 64, 32, 64, 32);
  rp_dec<<<cdiv_l(27L*64*128, TPB), TPB, 0, stream>>>(wt1c, wb1c, 128, 64, 128, 64);
  rp_dec<<<cdiv_l(27L*16*32, TPB), TPB, 0, stream>>>(wt0r, wbrec, 32, 16, 32, 16);
  rp_dec<<<cdiv_l(27L*16*96, TPB), TPB, 0, stream>>>(wt0c, wbcl, 96, 2, 96, 16);

  // ---- x -> NDHWC bf16 ----
  xpose_k<<<2048, TPB, 0, stream>>>(x, xt);

  auto bn = [&](unsigned short* t, const float* g, const float* b, int C, int lC, long npts) {
    bn_stats1_cl<<<K, TPB, 0, stream>>>(t, part, npts, C, lC, K);
    bn_stats2_k<<<1, 128, 0, stream>>>(part, g, b, bsc, bsh, C, K, 1.f / (float)(npts));
    long tot8 = npts * C / 8;
    bn_relu_cl<<<cdiv_l(tot8, TPB), TPB, 0, stream>>>(t, bsc, bsh, C, tot8);
  };

  auto gx = [&](int G){ return (unsigned)(N * (G >> 2) * (G >> 2) * (G >> 4)); };

  // ---- encoder ----
  mconv<0, 2, true, false><<<dim3(gx(64), 1), TPB, 0, stream>>>(
      xt, 16, nullptr, 0, wb0p, s1, N, 32, 32, 32, 64);
  bn(s1, g0, b0, 32, 5, 2 * sp64);
  mconv<2, 2, false, false><<<dim3(gx(32), 2), TPB, 0, stream>>>(
      s1, 32, nullptr, 0, wb1, s2, N, 64, 64, 32, 32);
  bn(s2, g1, b1, 64, 6, 2 * sp32);
  mconv<2, 2, false, false><<<dim3(gx(16), 4), TPB, 0, stream>>>(
      s2, 64, nullptr, 0, wb2, s4, N, 128, 128, 64, 16);
  bn(s4, g2, b2, 128, 7, 2 * sp16);

  // ---- level-2 tconvs (16 -> 32), quadrants ----
  tconv_quad<2><<<dim3(gx(16), 2, 4), TPB, 0, stream>>>(
      s4, 128, nullptr, 0, wb2r, r32, N, 64, 64, 128, 16);
  bn(r32, g2r, b2r, 64, 6, 2 * sp32);
  tconv_quad<2><<<dim3(gx(16), 2, 4), TPB, 0, stream>>>(
      s4, 128, nullptr, 0, wb2c, c32, N, 64, 64, 128, 16);
  bn(c32, g2c, b2c, 64, 6, 2 * sp32);

  // ---- level-1 tconvs (32 -> 64), quadrants ----
  tconv_quad<2><<<dim3(gx(32), 1, 4), TPB, 0, stream>>>(
      r32, 64, nullptr, 0, wb1r, r64, N, 32, 32, 64, 32);
  bn(r64, g1r, b1r, 32, 5, 2 * sp64);
  tconv_quad<4><<<dim3(gx(32), 1, 4), TPB, 0, stream>>>(
      c32, 64, s2, 64, wb1c, c64, N, 64, 64, 128, 32);
  bn(c64, g1c, b1c, 64, 6, 2 * sp64);

  // ---- level-0 stride-1 convs (no BN), LDS-staged -> fp32 NCDHW outputs ----
  mconv<0, 1, false, true><<<dim3(gx(64), 1), TPB, 0, stream>>>(
      r64, 32, nullptr, 0, wbrec, out_rec, N, 16, 16, 32, 64);
  mconv<0, 1, false, true><<<dim3(gx(64), 1), TPB, 0, stream>>>(
      c64, 64, s1, 32, wbcl, out_cl, N, 2, 16, 96, 64);
}

// Round 10
// 1040.211 us; speedup vs baseline: 3.7327x; 1.0479x over previous
//
#include <hip/hip_runtime.h>
#include <hip/hip_bf16.h>

// ---------------------------------------------------------------------------
// UNet3D dense forward, round 10: NDHWC implicit-GEMM MFMA.
//  - BN apply+ReLU fused into consumer staging for s4/r32/c32/r64/c64
//    (stats on raw tensor, per-layer scale/shift buffers; 239MB RW removed).
//  - V0 stride-1 convs: 2d x 8h x 16w tile (halo/pt 5.06 -> 2.81).
//  - tconv quadrant + V2 stride-2 unchanged from R9 (conflict-free LDS).
// ---------------------------------------------------------------------------

using bf16 = __hip_bfloat16;
using ushort4v = __attribute__((ext_vector_type(4))) unsigned short;
using ushort8  = __attribute__((ext_vector_type(8))) unsigned short;
using short8   = __attribute__((ext_vector_type(8))) short;
using f32x4    = __attribute__((ext_vector_type(4))) float;
using float4v  = __attribute__((ext_vector_type(4))) float;

#define TPB 256

static inline int cdiv_l(long a, int b){ return (int)((a + b - 1) / b); }

__device__ __forceinline__ float b2f(unsigned short u){
  union { unsigned int i; float f; } v; v.i = ((unsigned int)u) << 16; return v.f;
}
__device__ __forceinline__ unsigned short f2b(float f){
  union { bf16 h; unsigned short u; } v; v.h = __float2bfloat16(f); return v.u;
}
// BN+ReLU on 8 packed bf16 channels starting at channel c (8-aligned).
__device__ __forceinline__ ushort8 bnApply8(ushort8 v, const float* sc, const float* sh, int c){
  float4v s0 = *(const float4v*)(sc + c), s1v = *(const float4v*)(sc + c + 4);
  float4v h0 = *(const float4v*)(sh + c), h1v = *(const float4v*)(sh + c + 4);
  ushort8 r;
#pragma unroll
  for (int j = 0; j < 4; ++j){ float y = b2f(v[j]) * s0[j] + h0[j]; r[j] = f2b(y > 0.f ? y : 0.f); }
#pragma unroll
  for (int j = 0; j < 4; ++j){ float y = b2f(v[j+4]) * s1v[j] + h1v[j]; r[j+4] = f2b(y > 0.f ? y : 0.f); }
  return r;
}

// ---------------- weight repacks (bf16) ----------------
__global__ void rp_enc(const float* __restrict__ w, unsigned short* __restrict__ wb,
                       int Cin, int Cout){
  int idx = blockIdx.x * TPB + threadIdx.x;
  int tot = 27 * Cout * Cin; if (idx >= tot) return;
  int ci = idx % Cin; int t = idx / Cin; int co = t % Cout; int tap = t / Cout;
  wb[idx] = f2b(w[((long)co * Cin + ci) * 27 + tap]);
}
__global__ void rp_dec(const float* __restrict__ w, unsigned short* __restrict__ wb,
                       int Cin, int Cout, int CIP, int COP){
  int idx = blockIdx.x * TPB + threadIdx.x;
  int tot = 27 * COP * CIP; if (idx >= tot) return;
  int ci = idx % CIP; int t = idx / CIP; int co = t % COP; int tap = t / COP;
  float v = (ci < Cin && co < Cout) ? w[((long)tap * Cin + ci) * Cout + co] : 0.f;
  wb[idx] = f2b(v);
}
// conv0 tap-paired: [pp<14][co<32][k<32]
__global__ void rp_pair(const float* __restrict__ w, unsigned short* __restrict__ wb){
  int idx = blockIdx.x * TPB + threadIdx.x;
  int tot = 14 * 32 * 32; if (idx >= tot) return;
  int k = idx & 31; int t = idx >> 5; int co = t & 31; int pp = t >> 5;
  int tap = pp * 2 + (k >> 4); int ci = k & 15;
  float v = (tap < 27) ? w[((long)co * 16 + ci) * 27 + tap] : 0.f;
  wb[idx] = f2b(v);
}

// ---------------- x transpose: NCDHW fp32 -> NDHWC bf16 (C=16) ----------------
__global__ void xpose_k(const float* __restrict__ x, unsigned short* __restrict__ xt){
  __shared__ float l[16][257];
  int t = threadIdx.x;
  long p0 = (long)blockIdx.x * 256;
  int n = (int)(p0 >> 18);
  long off = p0 & 262143;
  const float* xb = x + ((long)n * 16) * 262144 + off;
#pragma unroll
  for (int c = 0; c < 16; ++c) l[c][t] = xb[(long)c * 262144 + t];
  __syncthreads();
  ushort8 u0, u1;
#pragma unroll
  for (int k = 0; k < 8; ++k){ u0[k] = f2b(l[k][t]); u1[k] = f2b(l[k + 8][t]); }
  unsigned short* o = xt + (p0 + t) * 16;
  *(ushort8*)o = u0; *(ushort8*)(o + 8) = u1;
}

// ---------------- quadrant stride-2 tconv, LDS-staged, fused BN on A -------
template <int CO_TILES>
__global__ __launch_bounds__(TPB, 2) void tconv_quad(
    const unsigned short* __restrict__ inA, int CA,
    const unsigned short* __restrict__ inB, int CB,
    const float* __restrict__ scA, const float* __restrict__ shA,
    const unsigned short* __restrict__ wb,
    unsigned short* __restrict__ out,
    int N, int Cout, int COP, int CIP, int G) {
  __shared__ unsigned short xs[4 * 432 * 8];
  const int tid = threadIdx.x, wv = tid >> 6, l = tid & 63, l15 = l & 15, lg = l >> 4;
  int ntW = G >> 4, ntH = G >> 2, ntD = G >> 2;
  int bx = blockIdx.x;
  int w0 = (bx % ntW) << 4; bx /= ntW;
  int h0 = (bx % ntH) << 2; bx /= ntH;
  int d0 = (bx % ntD) << 2; int n = bx / ntD;
  const int co0 = blockIdx.y * (16 * CO_TILES);
  const int quad = blockIdx.z;
  const int pd = (quad >> 1) & 1, ph = quad & 1;
  const long spin = (long)G * G * G;

  int nkd, kd_[2], dd_[2], nkh, kh_[2], dh_[2];
  if (pd){ nkd=1; kd_[0]=1; dd_[0]=0; } else { nkd=2; kd_[0]=0; dd_[0]=-1; kd_[1]=2; dd_[1]=0; }
  if (ph){ nkh=1; kh_[0]=1; dh_[0]=0; } else { nkh=2; kh_[0]=0; dh_[0]=-1; kh_[1]=2; dh_[1]=0; }

  f32x4 acc[CO_TILES][4][2];
#pragma unroll
  for (int ct = 0; ct < CO_TILES; ++ct)
#pragma unroll
    for (int j = 0; j < 4; ++j)
#pragma unroll
      for (int p = 0; p < 2; ++p) acc[ct][j][p] = (f32x4){0.f, 0.f, 0.f, 0.f};

  const int nch = CIP >> 5;
#pragma unroll 1
  for (int ch = 0; ch < nch; ++ch) {
    int c0 = ch << 5;
    const unsigned short* src; int Cs, cl_; bool useBN;
    if (c0 < CA){ src = inA; Cs = CA; cl_ = c0; useBN = (scA != nullptr); }
    else        { src = inB; Cs = CB; cl_ = c0 - CA; useBN = false; }
    const unsigned short* sb = src + (long)n * Cs * spin;
    __syncthreads();
    for (int idx = tid; idx < 4 * 425; idx += TPB) {
      int q = idx / 425, pt = idx - q * 425;
      int zw = pt % 17; int zt = pt / 17; int zh = zt % 5; int zd = zt / 5;
      int gd = d0 + zd - 1, gh = h0 + zh - 1, gw = w0 + zw - 1;
      ushort8 v = (ushort8){0,0,0,0,0,0,0,0};
      if ((unsigned)gd < (unsigned)G && (unsigned)gh < (unsigned)G && (unsigned)gw < (unsigned)G) {
        v = *(const ushort8*)(sb + (((long)gd * G + gh) * G + gw) * Cs + cl_ + q * 8);
        if (useBN) v = bnApply8(v, scA, shA, cl_ + q * 8);
      }
      *(ushort8*)(xs + (q * 432 + pt) * 8) = v;
    }
    __syncthreads();
#pragma unroll 1
    for (int a = 0; a < nkd; ++a) {
      int zd = wv + 1 + dd_[a];
#pragma unroll 1
      for (int b = 0; b < nkh; ++b) {
        int tapb = (kd_[a] * 3 + kh_[b]) * 3;
        const unsigned short* ap = wb + ((long)tapb * COP + co0 + l15) * CIP + c0 + lg * 8;
        long tstride = (long)COP * CIP;
        short8 Ak0[CO_TILES], Ak1[CO_TILES], Ak2[CO_TILES];
#pragma unroll
        for (int ct = 0; ct < CO_TILES; ++ct) {
          Ak0[ct] = *(const short8*)(ap + ct * 16 * CIP);
          Ak1[ct] = *(const short8*)(ap + tstride + ct * 16 * CIP);
          Ak2[ct] = *(const short8*)(ap + 2 * tstride + ct * 16 * CIP);
        }
        int zh0 = 1 + dh_[b];
#pragma unroll
        for (int j = 0; j < 4; ++j) {
          int basept = (zd * 5 + (j + zh0)) * 17 + l15;
          short8 Bm = *(const short8*)(xs + (lg * 432 + basept) * 8);
          short8 B0 = *(const short8*)(xs + (lg * 432 + basept + 1) * 8);
#pragma unroll
          for (int ct = 0; ct < CO_TILES; ++ct) {
            acc[ct][j][0] = __builtin_amdgcn_mfma_f32_16x16x32_bf16(Ak0[ct], Bm, acc[ct][j][0], 0, 0, 0);
            acc[ct][j][0] = __builtin_amdgcn_mfma_f32_16x16x32_bf16(Ak2[ct], B0, acc[ct][j][0], 0, 0, 0);
            acc[ct][j][1] = __builtin_amdgcn_mfma_f32_16x16x32_bf16(Ak1[ct], B0, acc[ct][j][1], 0, 0, 0);
          }
        }
      }
    }
  }

  // ---- dense store ----
  int Gout = 2 * G; long spo = (long)Gout * Gout * Gout;
  int od = 2 * (d0 + wv) + pd;
#pragma unroll
  for (int j = 0; j < 4; ++j) {
    int oh = 2 * (h0 + j) + ph;
#pragma unroll
    for (int p = 0; p < 2; ++p) {
      int ow = 2 * (w0 + l15) + p;
      long pt = ((long)od * Gout + oh) * Gout + ow;
#pragma unroll
      for (int ct = 0; ct < CO_TILES; ++ct) {
        ushort4v pk;
#pragma unroll
        for (int r = 0; r < 4; ++r) pk[r] = f2b(acc[ct][j][p][r]);
        *(ushort4v*)(out + ((long)n * spo + pt) * Cout + co0 + ct * 16 + lg * 4) = pk;
      }
    }
  }
}

// ---------------- unified NDHWC MFMA conv ----------------
// VARIANT 0 / PAIRED: stride-1 conv, LDS-staged, tile 2d x 8h x 16w.
//   wave wv: wvd = wv&1 (d-slice), jh = wv>>1 (h-half, 4 j-rows each).
// VARIANT 2: stride-2 conv, direct-global B, tile 4d x 4h x 16w.
template <int VARIANT, int CO_TILES, bool PAIRED, bool FOUT>
__global__ __launch_bounds__(TPB) void mconv(
    const unsigned short* __restrict__ inA, int CA,
    const unsigned short* __restrict__ inB, int CB,
    const float* __restrict__ scA, const float* __restrict__ shA,
    const unsigned short* __restrict__ wb,
    void* __restrict__ outv,
    int N, int Cout, int COP, int CIP, int G) {
  const int tid = threadIdx.x, wv = tid >> 6, l = tid & 63, l15 = l & 15, lg = l >> 4;
  int bx = blockIdx.x;
  int w0, h0, d0, n;
  int wvd = wv & 1, jh = wv >> 1, jbase = jh * 4;
  if constexpr (VARIANT == 0) {
    int ntW = G >> 4, ntH = G >> 3, ntD = G >> 1;
    w0 = (bx % ntW) << 4; bx /= ntW;
    h0 = (bx % ntH) << 3; bx /= ntH;
    d0 = (bx % ntD) << 1; n = bx / ntD;
  } else {
    int ntW = G >> 4, ntH = G >> 2, ntD = G >> 2;
    w0 = (bx % ntW) << 4; bx /= ntW;
    h0 = (bx % ntH) << 2; bx /= ntH;
    d0 = (bx % ntD) << 2; n = bx / ntD;
  }
  const int co0 = blockIdx.y * (16 * CO_TILES);
  const int Gin = (VARIANT == 2) ? 2 * G : G;
  const long spin = (long)Gin * Gin * Gin;

  f32x4 acc[CO_TILES][4];
#pragma unroll
  for (int ct = 0; ct < CO_TILES; ++ct)
#pragma unroll
    for (int j = 0; j < 4; ++j) acc[ct][j] = (f32x4){0.f, 0.f, 0.f, 0.f};

  if constexpr (PAIRED) {
    // conv0: Cin=16, K packs 2 taps; raw input (no BN).
    __shared__ unsigned short xs[2 * 728 * 8];
    const unsigned short* src = inA + (long)n * 16 * spin;
    for (int idx = tid; idx < 2 * 720; idx += TPB) {
      int q = idx / 720, pt = idx - q * 720;
      int zw = pt % 18; int zt = pt / 18; int zh = zt % 10; int zd = zt / 10;
      int gd = d0 + zd - 1, gh = h0 + zh - 1, gw = w0 + zw - 1;
      ushort8 v = (ushort8){0,0,0,0,0,0,0,0};
      if ((unsigned)gd < (unsigned)G && (unsigned)gh < (unsigned)G && (unsigned)gw < (unsigned)G)
        v = *(const ushort8*)(src + (((long)gd * G + gh) * G + gw) * 16 + q * 8);
      *(ushort8*)(xs + (q * 728 + pt) * 8) = v;
    }
    __syncthreads();
#pragma unroll 1
    for (int pp = 0; pp < 14; ++pp) {
      short8 A0 = *(const short8*)(wb + ((pp * 32 + l15) * 32) + lg * 8);
      short8 A1 = *(const short8*)(wb + ((pp * 32 + 16 + l15) * 32) + lg * 8);
      int t0 = 2 * pp + (lg >> 1); if (t0 > 26) t0 = 26;
      int dd = t0 / 9 - 1, dh = (t0 / 3) % 3 - 1, dw = t0 % 3 - 1;
      int q = lg & 1;
      int zd = wvd + 1 + dd;
      int base = (q * 728 + (zd * 10 + (1 + dh + jbase)) * 18 + 1 + l15 + dw) * 8;
#pragma unroll
      for (int j = 0; j < 4; ++j) {
        short8 B = *(const short8*)(xs + base + j * (18 * 8));
        acc[0][j] = __builtin_amdgcn_mfma_f32_16x16x32_bf16(A0, B, acc[0][j], 0, 0, 0);
        if (CO_TILES == 2)
          acc[1][j] = __builtin_amdgcn_mfma_f32_16x16x32_bf16(A1, B, acc[1][j], 0, 0, 0);
      }
    }
  } else if constexpr (VARIANT == 0) {
    // stride-1 conv: s=b+j row-sharing; fused BN on A-source chunks.
    __shared__ unsigned short xs[4 * 728 * 8];
    const int nch = CIP >> 5;
#pragma unroll 1
    for (int ch = 0; ch < nch; ++ch) {
      int c0 = ch << 5;
      const unsigned short* src; int Cs, cl_; bool useBN;
      if (c0 < CA){ src = inA; Cs = CA; cl_ = c0; useBN = (scA != nullptr); }
      else        { src = inB; Cs = CB; cl_ = c0 - CA; useBN = false; }
      const unsigned short* sb = src + (long)n * Cs * spin;
      __syncthreads();
      for (int idx = tid; idx < 4 * 720; idx += TPB) {
        int q = idx / 720, pt = idx - q * 720;
        int zw = pt % 18; int zt = pt / 18; int zh = zt % 10; int zd = zt / 10;
        int gd = d0 + zd - 1, gh = h0 + zh - 1, gw = w0 + zw - 1;
        ushort8 v = (ushort8){0,0,0,0,0,0,0,0};
        if ((unsigned)gd < (unsigned)G && (unsigned)gh < (unsigned)G && (unsigned)gw < (unsigned)G) {
          v = *(const ushort8*)(sb + (((long)gd * G + gh) * G + gw) * Cs + cl_ + q * 8);
          if (useBN) v = bnApply8(v, scA, shA, cl_ + q * 8);
        }
        *(ushort8*)(xs + (q * 728 + pt) * 8) = v;
      }
      __syncthreads();
#pragma unroll 1
      for (int a = 0; a < 3; ++a) {
        int zd = wvd + a;
        short8 A0[3][3], A1[3][3];
#pragma unroll
        for (int b = 0; b < 3; ++b)
#pragma unroll
          for (int c = 0; c < 3; ++c) {
            int tap = (a * 3 + b) * 3 + c;
            const unsigned short* ap = wb + ((long)tap * COP + co0 + l15) * CIP + c0 + lg * 8;
            A0[b][c] = *(const short8*)ap;
            if (CO_TILES == 2) A1[b][c] = *(const short8*)(ap + 16 * CIP);
          }
#pragma unroll
        for (int sl = 0; sl < 6; ++sl) {
          int sg = jbase + sl;
          int rb = (lg * 728 + (zd * 10 + sg) * 18 + l15) * 8;
          short8 B0 = *(const short8*)(xs + rb);
          short8 B1 = *(const short8*)(xs + rb + 8);
          short8 B2 = *(const short8*)(xs + rb + 16);
#pragma unroll
          for (int b = 0; b < 3; ++b) {
            int j = sl - b;
            if (j >= 0 && j < 4) {
              acc[0][j] = __builtin_amdgcn_mfma_f32_16x16x32_bf16(A0[b][0], B0, acc[0][j], 0, 0, 0);
              acc[0][j] = __builtin_amdgcn_mfma_f32_16x16x32_bf16(A0[b][1], B1, acc[0][j], 0, 0, 0);
              acc[0][j] = __builtin_amdgcn_mfma_f32_16x16x32_bf16(A0[b][2], B2, acc[0][j], 0, 0, 0);
              if (CO_TILES == 2) {
                acc[1][j] = __builtin_amdgcn_mfma_f32_16x16x32_bf16(A1[b][0], B0, acc[1][j], 0, 0, 0);
                acc[1][j] = __builtin_amdgcn_mfma_f32_16x16x32_bf16(A1[b][1], B1, acc[1][j], 0, 0, 0);
                acc[1][j] = __builtin_amdgcn_mfma_f32_16x16x32_bf16(A1[b][2], B2, acc[1][j], 0, 0, 0);
              }
            }
          }
        }
      }
    }
  } else {
    // VARIANT 2: stride-2 conv, direct-global B (inputs pre-normalized).
    const int nch = CIP >> 5;
#pragma unroll 1
    for (int ch = 0; ch < nch; ++ch) {
      int c0 = ch << 5;
      const unsigned short* src; int Cs, cl_;
      if (c0 < CA){ src = inA; Cs = CA; cl_ = c0; } else { src = inB; Cs = CB; cl_ = c0 - CA; }
      const unsigned short* sb = src + (long)n * Cs * spin;
#pragma unroll 1
      for (int a = 0; a < 3; ++a) {
        int gd = 2 * (d0 + wv) + a - 1;
        bool vd = (unsigned)gd < (unsigned)Gin;
#pragma unroll 1
        for (int b = 0; b < 3; ++b) {
#pragma unroll
          for (int c = 0; c < 3; ++c) {
            int tap = (a * 3 + b) * 3 + c;
            const unsigned short* ap = wb + ((long)tap * COP + co0 + l15) * CIP + c0 + lg * 8;
            short8 A0 = *(const short8*)ap;
            short8 A1;
            if (CO_TILES == 2) A1 = *(const short8*)(ap + 16 * CIP);
            int gw = 2 * (w0 + l15) + c - 1;
            bool vdw = vd && ((unsigned)gw < (unsigned)Gin);
#pragma unroll
            for (int j = 0; j < 4; ++j) {
              int gh = 2 * (h0 + j) + b - 1;
              short8 B = (short8){0,0,0,0,0,0,0,0};
              if (vdw && (unsigned)gh < (unsigned)Gin)
                B = *(const short8*)(sb + (((long)gd * Gin + gh) * Gin + gw) * Cs + cl_ + lg * 8);
              acc[0][j] = __builtin_amdgcn_mfma_f32_16x16x32_bf16(A0, B, acc[0][j], 0, 0, 0);
              if (CO_TILES == 2)
                acc[1][j] = __builtin_amdgcn_mfma_f32_16x16x32_bf16(A1, B, acc[1][j], 0, 0, 0);
            }
          }
        }
      }
    }
  }

  // ---- store ----
  const long spo = (long)G * G * G;
#pragma unroll
  for (int j = 0; j < 4; ++j) {
    long pt;
    if constexpr (VARIANT == 0)
      pt = ((long)(d0 + wvd) * G + (h0 + jbase + j)) * G + (w0 + l15);
    else
      pt = ((long)(d0 + wv) * G + (h0 + j)) * G + (w0 + l15);
    if constexpr (!FOUT) {
      unsigned short* outp = (unsigned short*)outv;
#pragma unroll
      for (int ct = 0; ct < CO_TILES; ++ct) {
        ushort4v pk;
#pragma unroll
        for (int r = 0; r < 4; ++r) pk[r] = f2b(acc[ct][j][r]);
        *(ushort4v*)(outp + ((long)n * spo + pt) * Cout + co0 + ct * 16 + lg * 4) = pk;
      }
    } else {
      float* outp = (float*)outv;
#pragma unroll
      for (int ct = 0; ct < CO_TILES; ++ct)
#pragma unroll
        for (int r = 0; r < 4; ++r) {
          int co = co0 + ct * 16 + lg * 4 + r;
          if (co < Cout) outp[((long)(n * Cout + co)) * spo + pt] = acc[ct][j][r];
        }
    }
  }
}

// ---------------- BN stats stage 1 (channels-last, raw tensor) ----------------
__global__ void bn_stats1_cl(const unsigned short* __restrict__ x, float* __restrict__ part,
                             long npts, int C, int lC, int K){
  int chunk = blockIdx.x, tid = threadIdx.x;
  int c = tid & (C - 1); int pr = tid >> lC; int PR = TPB >> lC;
  float s = 0.f, q = 0.f;
  for (long p = (long)chunk * PR + pr; p < npts; p += (long)K * PR) {
    float f = b2f(x[p * C + c]); s += f; q += f * f;
  }
  __shared__ float shs[TPB], shq[TPB];
  shs[tid] = s; shq[tid] = q;
  __syncthreads();
  for (int off = TPB / 2; off >= C; off >>= 1) {
    if (tid < off) { shs[tid] += shs[tid + off]; shq[tid] += shq[tid + off]; }
    __syncthreads();
  }
  if (tid < C) { part[((long)tid * K + chunk) * 2] = shs[tid]; part[((long)tid * K + chunk) * 2 + 1] = shq[tid]; }
}

// ---------------- BN stats stage 2 -> scale/shift ----------------
__global__ void bn_stats2_k(const float* __restrict__ part, const float* __restrict__ g,
                            const float* __restrict__ b, float* __restrict__ scale,
                            float* __restrict__ shift, int C, int K, float inv_cnt) {
  int c = blockIdx.x * blockDim.x + threadIdx.x;
  if (c >= C) return;
  float s = 0.f, q = 0.f;
  for (int k = 0; k < K; ++k) { s += part[((long)c * K + k) * 2]; q += part[((long)c * K + k) * 2 + 1]; }
  float m = s * inv_cnt, v = q * inv_cnt - m * m;
  float rs = rsqrtf(v + 1e-5f) * g[c];
  scale[c] = rs;
  shift[c] = b[c] - m * rs;
}

// ---------------- BN apply + ReLU pass (for s1, s2 only) ----------------
__global__ void bn_relu_cl(unsigned short* __restrict__ x, const float* __restrict__ sc,
                           const float* __restrict__ sh, int C, long tot8){
  long i8 = (long)blockIdx.x * TPB + threadIdx.x;
  if (i8 >= tot8) return;
  long e = i8 * 8;
  int c0 = (int)(e & (C - 1));
  ushort8 v = *(ushort8*)(x + e);
  *(ushort8*)(x + e) = bnApply8(v, sc, sh, c0);
}

extern "C" void kernel_launch(void* const* d_in, const int* in_sizes, int n_in,
                              void* d_out, int out_size, void* d_ws, size_t ws_size,
                              hipStream_t stream) {
  const float* x    = (const float*)d_in[0];
  const float* w0   = (const float*)d_in[1];
  const float* g0   = (const float*)d_in[2];
  const float* b0   = (const float*)d_in[3];
  const float* w1   = (const float*)d_in[4];
  const float* g1   = (const float*)d_in[5];
  const float* b1   = (const float*)d_in[6];
  const float* w2   = (const float*)d_in[7];
  const float* g2   = (const float*)d_in[8];
  const float* b2   = (const float*)d_in[9];
  const float* wt2r = (const float*)d_in[10];
  const float* g2r  = (const float*)d_in[11];
  const float* b2r  = (const float*)d_in[12];
  const float* wt1r = (const float*)d_in[13];
  const float* g1r  = (const float*)d_in[14];
  const float* b1r  = (const float*)d_in[15];
  const float* wt0r = (const float*)d_in[16];
  const float* wt2c = (const float*)d_in[17];
  const float* g2c  = (const float*)d_in[18];
  const float* b2c  = (const float*)d_in[19];
  const float* wt1c = (const float*)d_in[20];
  const float* g1c  = (const float*)d_in[21];
  const float* b1c  = (const float*)d_in[22];
  const float* wt0c = (const float*)d_in[23];

  const int N = 2;
  const long sp64 = 262144, sp32 = 32768, sp16 = 4096;
  const int K = 256;  // bn chunks

  // ---- workspace (ushort units), all activations NDHWC bf16 ----
  unsigned short* W = (unsigned short*)d_ws;
  unsigned short* s1   = W;                       // [2*sp64][32]
  unsigned short* s2   = s1  + 16777216;          // [2*sp32][64]
  unsigned short* s4   = s2  + 4194304;           // [2*sp16][128]
  unsigned short* r32  = s4  + 1048576;           // [2*sp32][64]
  unsigned short* c32  = r32 + 4194304;           // [2*sp32][64]
  unsigned short* r64  = c32 + 4194304;           // [2*sp64][32]
  unsigned short* xt   = r64;                     // alias (dead after conv0)
  unsigned short* c64  = r64 + 16777216;          // [2*sp64][64]
  unsigned short* wb0p = c64 + 33554432;          // 14*32*32
  unsigned short* wb1  = wb0p + 14336;            // 27*64*32
  unsigned short* wb2  = wb1  + 55296;            // 27*128*64
  unsigned short* wb2r = wb2  + 221184;           // 27*64*128
  unsigned short* wb2c = wb2r + 221184;
  unsigned short* wb1r = wb2c + 221184;           // 27*32*64
  unsigned short* wb1c = wb1r + 55296;            // 27*64*128
  unsigned short* wbrec= wb1c + 221184;           // 27*16*32
  unsigned short* wbcl = wbrec+ 13824;            // 27*16*96
  float* part = (float*)(wbcl + 41472);
  float* bsc  = part + 128L * K * 2;              // shared (s1, s2)
  float* bsh  = bsc + 128;
  float* sc_s4  = bsh  + 128; float* sh_s4  = sc_s4  + 128;
  float* sc_r32 = sh_s4 + 128; float* sh_r32 = sc_r32 + 128;
  float* sc_c32 = sh_r32+ 128; float* sh_c32 = sc_c32 + 128;
  float* sc_r64 = sh_c32+ 128; float* sh_r64 = sc_r64 + 128;
  float* sc_c64 = sh_r64+ 128; float* sh_c64 = sc_c64 + 128;

  float* out_cl  = (float*)d_out;                 // [2][2][64^3] NCDHW
  float* out_rec = (float*)d_out + 2L * 2 * sp64; // [2][16][64^3]

  // ---- weight repacks ----
  rp_pair<<<cdiv_l(14L*32*32, TPB), TPB, 0, stream>>>(w0, wb0p);
  rp_enc<<<cdiv_l(27L*64*32, TPB), TPB, 0, stream>>>(w1, wb1, 32, 64);
  rp_enc<<<cdiv_l(27L*128*64, TPB), TPB, 0, stream>>>(w2, wb2, 64, 128);
  rp_dec<<<cdiv_l(27L*64*128, TPB), TPB, 0, stream>>>(wt2r, wb2r, 128, 64, 128, 64);
  rp_dec<<<cdiv_l(27L*64*128, TPB), TPB, 0, stream>>>(wt2c, wb2c, 128, 64, 128, 64);
  rp_dec<<<cdiv_l(27L*32*64, TPB), TPB, 0, stream>>>(wt1r, wb1r, 64, 32, 64, 32);
  rp_dec<<<cdiv_l(27L*64*128, TPB), TPB, 0, stream>>>(wt1c, wb1c, 128, 64, 128, 64);
  rp_dec<<<cdiv_l(27L*16*32, TPB), TPB, 0, stream>>>(wt0r, wbrec, 32, 16, 32, 16);
  rp_dec<<<cdiv_l(27L*16*96, TPB), TPB, 0, stream>>>(wt0c, wbcl, 96, 2, 96, 16);

  // ---- x -> NDHWC bf16 ----
  xpose_k<<<2048, TPB, 0, stream>>>(x, xt);

  // stats (raw) -> scale/shift; optional in-place apply
  auto bnStats = [&](unsigned short* t, const float* g, const float* b, int C, int lC,
                     long npts, float* sc, float* sh) {
    bn_stats1_cl<<<K, TPB, 0, stream>>>(t, part, npts, C, lC, K);
    bn_stats2_k<<<1, 128, 0, stream>>>(part, g, b, sc, sh, C, K, 1.f / (float)(npts));
  };
  auto bnFull = [&](unsigned short* t, const float* g, const float* b, int C, int lC, long npts) {
    bnStats(t, g, b, C, lC, npts, bsc, bsh);
    long tot8 = npts * C / 8;
    bn_relu_cl<<<cdiv_l(tot8, TPB), TPB, 0, stream>>>(t, bsc, bsh, C, tot8);
  };

  // grids: V0/PAIRED = 2d x 8h x 16w tiles; V2/tconv = 4d x 4h x 16w
  auto gx0 = [&](int G){ return (unsigned)(N * (G >> 1) * (G >> 3) * (G >> 4)); };
  auto gx  = [&](int G){ return (unsigned)(N * (G >> 2) * (G >> 2) * (G >> 4)); };

  // ---- encoder ----
  mconv<0, 2, true, false><<<dim3(gx0(64), 1), TPB, 0, stream>>>(
      xt, 16, nullptr, 0, nullptr, nullptr, wb0p, s1, N, 32, 32, 32, 64);
  bnFull(s1, g0, b0, 32, 5, 2 * sp64);
  mconv<2, 2, false, false><<<dim3(gx(32), 2), TPB, 0, stream>>>(
      s1, 32, nullptr, 0, nullptr, nullptr, wb1, s2, N, 64, 64, 32, 32);
  bnFull(s2, g1, b1, 64, 6, 2 * sp32);
  mconv<2, 2, false, false><<<dim3(gx(16), 4), TPB, 0, stream>>>(
      s2, 64, nullptr, 0, nullptr, nullptr, wb2, s4, N, 128, 128, 64, 16);
  bnStats(s4, g2, b2, 128, 7, 2 * sp16, sc_s4, sh_s4);

  // ---- level-2 tconvs (16 -> 32), quadrants; BN(s4) fused on load ----
  tconv_quad<2><<<dim3(gx(16), 2, 4), TPB, 0, stream>>>(
      s4, 128, nullptr, 0, sc_s4, sh_s4, wb2r, r32, N, 64, 64, 128, 16);
  bnStats(r32, g2r, b2r, 64, 6, 2 * sp32, sc_r32, sh_r32);
  tconv_quad<2><<<dim3(gx(16), 2, 4), TPB, 0, stream>>>(
      s4, 128, nullptr, 0, sc_s4, sh_s4, wb2c, c32, N, 64, 64, 128, 16);
  bnStats(c32, g2c, b2c, 64, 6, 2 * sp32, sc_c32, sh_c32);

  // ---- level-1 tconvs (32 -> 64), quadrants ----
  tconv_quad<2><<<dim3(gx(32), 1, 4), TPB, 0, stream>>>(
      r32, 64, nullptr, 0, sc_r32, sh_r32, wb1r, r64, N, 32, 32, 64, 32);
  bnStats(r64, g1r, b1r, 32, 5, 2 * sp64, sc_r64, sh_r64);
  tconv_quad<4><<<dim3(gx(32), 1, 4), TPB, 0, stream>>>(
      c32, 64, s2, 64, sc_c32, sh_c32, wb1c, c64, N, 64, 64, 128, 32);
  bnStats(c64, g1c, b1c, 64, 6, 2 * sp64, sc_c64, sh_c64);

  // ---- level-0 stride-1 convs (no BN on output), fused BN on inputs ----
  mconv<0, 1, false, true><<<dim3(gx0(64), 1), TPB, 0, stream>>>(
      r64, 32, nullptr, 0, sc_r64, sh_r64, wbrec, out_rec, N, 16, 16, 32, 64);
  mconv<0, 1, false, true><<<dim3(gx0(64), 1), TPB, 0, stream>>>(
      c64, 64, s1, 32, sc_c64, sh_c64, wbcl, out_cl, N, 2, 16, 96, 64);
}